// Round 1
// baseline (4989.378 us; speedup 1.0000x reference)
//
#include <hip/hip_runtime.h>

#define DEVFN static __device__ __forceinline__

namespace {
constexpr int Bc = 16, Sc = 16, Hc = 501, HP = 512, Cc = 10, LATc = 56, Gc = 517;
constexpr int H2c = 1002, H3c = 1503, H4c = 2004;
constexpr int NBLK = 256, NTHR = 256;

// ---- workspace layout (float offsets) ----
constexpr size_t OFF_WG   = 0;                                   // gate_w[:, :H] repacked 501x512 (zero pad)
constexpr size_t OFF_WM   = OFF_WG   + (size_t)Hc * HP;          // map_w[:, :H]
constexpr size_t OFF_WHH  = OFF_WM   + (size_t)Hc * HP;          // gru_w_hh 1503x512
constexpr size_t OFF_WHV  = OFF_WHH  + (size_t)H3c * HP;         // ae1_w[:, :H] 2004x512
constexpr size_t OFF_WHJ  = OFF_WHV  + (size_t)H4c * HP;         // ae1_w[:, H:] 2004x512
constexpr size_t OFF_WAV1 = OFF_WHJ  + (size_t)H4c * HP;         // av1_w 1002x512
constexpr size_t OFF_QTAB = OFF_WAV1 + (size_t)H2c * HP;         // Q table [b][j][512] (rows j<index finalized)
constexpr size_t OFF_MTAB = OFF_QTAB + (size_t)Bc * Sc * HP;
constexpr size_t OFF_HSEQ = OFF_MTAB + (size_t)Bc * Sc * HP;     // hv history [b][index][s][512], write-once slots
constexpr size_t OFF_GI   = OFF_HSEQ + (size_t)Bc * Sc * 16 * HP;// gi_all [b][idx][1536]
constexpr size_t OFF_GS0  = OFF_GI   + (size_t)Bc * Sc * 1536;   // lin1(z) [b][512]
constexpr size_t OFF_HINS = OFF_GS0  + (size_t)Bc * HP;          // h_in versioned [tri(index,s)][b][512]
constexpr size_t OFF_BHJ  = OFF_HINS + (size_t)120 * Bc * HP;    // W_hj @ nhs_j  [b][j<15][2048]
constexpr size_t OFF_TBUF = OFF_BHJ  + (size_t)Bc * 15 * 2048;   // relu(av1@gs) [b][idx][1024]
constexpr size_t WS_FLOATS= OFF_TBUF + (size_t)Bc * Sc * 1024;
constexpr int    NBAR = 280;
constexpr size_t BAR_STRIDE = 40;       // uints per barrier: 32 leaf + 1 root (+pad)
constexpr size_t WS_BYTES_NEEDED = WS_FLOATS * 4 + (NBAR * BAR_STRIDE + 64) * 4;
} // namespace

DEVFN float sigf(float x)  { return 1.0f / (1.0f + __expf(-x)); }
DEVFN float tanhf_(float x){ float e2 = __expf(2.0f * x); return 1.0f - 2.0f / (e2 + 1.0f); }

// device-coherent (L1/L2-bypass) store/load: keeps normal caches free of stale lines
DEVFN void  stg(float* p, float v) { __hip_atomic_store(p, v, __ATOMIC_RELAXED, __HIP_MEMORY_SCOPE_AGENT); }

DEVFN size_t hslot(int b, int idx, int s) { return OFF_HSEQ + (((size_t)b * 16 + idx) * 16 + s) * HP; }

struct KArgs {
  const float* in[21];
  float* out;
  float* wsf;
  unsigned* bar;
};

// tree barrier: 32 leaf counters (8 blocks each) + root. Relaxed agent atomics only;
// __syncthreads() at entry drains each wave's vmem (bypass stores already at LLC).
DEVFN void gbar(unsigned* bar, int& id, bool heavy) {
  __syncthreads();
  if (heavy) __threadfence();          // flush plain-written (constant) init data to LLC, once
  if (threadIdx.x == 0) {
    unsigned* p = bar + (size_t)id * BAR_STRIDE;
    int g = blockIdx.x >> 3;
    unsigned r = __hip_atomic_fetch_add(p + g, 1u, __ATOMIC_RELAXED, __HIP_MEMORY_SCOPE_AGENT);
    if (r == 7u)
      __hip_atomic_fetch_add(p + 32, 1u, __ATOMIC_RELAXED, __HIP_MEMORY_SCOPE_AGENT);
    while (__hip_atomic_load(p + 32, __ATOMIC_RELAXED, __HIP_MEMORY_SCOPE_AGENT) < 32u)
      __builtin_amdgcn_s_sleep(1);
  }
  __syncthreads();
  ++id;
}

__global__ __launch_bounds__(NTHR, 1) void Decoder_20014547599839_kernel(KArgs a) {
  const int blk = blockIdx.x, tid = threadIdx.x;
  const int gtid = blk * NTHR + tid;
  const int NTH = NBLK * NTHR;
  float* wsf = a.wsf;
  unsigned* bar = a.bar;
  int barid = 0;

  __shared__ float lds_h[8192];    // 32KB staging (hv / h_in / F-phase vector sets)
  __shared__ float lds_ps[32 * 16];// per-(i,v) prefix sums, persists across one index's scan
  __shared__ float lds_red[260];

  const float* z    = a.in[0];  const float* dep  = a.in[1];  const float* enc  = a.in[2];
  const float* lin1w= a.in[3];  const float* lin1b= a.in[4];
  const float* av1w = a.in[5];  const float* av1b = a.in[6];
  const float* av2w = a.in[7];  const float* av2b = a.in[8];
  const float* ae1w = a.in[9];  const float* ae1b = a.in[10];
  const float* ae2w = a.in[11]; const float* ae2b = a.in[12];
  const float* gatew= a.in[13]; const float* gateb= a.in[14];
  const float* mapw = a.in[15]; const float* mapb = a.in[16];
  const float* wih  = a.in[17]; const float* bih  = a.in[18];
  const float* whh  = a.in[19]; const float* bhh  = a.in[20];

  // ---------- barrier bring-up (ws is poisoned 0xAA each launch) ----------
  if (blk == 0) {
    for (int t = tid; t < NBAR * (int)BAR_STRIDE; t += NTHR)
      __hip_atomic_store(bar + t, 0u, __ATOMIC_RELAXED, __HIP_MEMORY_SCOPE_AGENT);
    __syncthreads();
    if (tid == 0)
      __hip_atomic_store(bar + NBAR * BAR_STRIDE, 0x13572468u, __ATOMIC_RELEASE, __HIP_MEMORY_SCOPE_AGENT);
  } else if (tid == 0) {
    while (__hip_atomic_load(bar + NBAR * BAR_STRIDE, __ATOMIC_ACQUIRE, __HIP_MEMORY_SCOPE_AGENT) != 0x13572468u)
      __builtin_amdgcn_s_sleep(1);
  }
  __syncthreads();

  // ---------- INIT: repack weights (padded rows), gi_all, gs0, zero outputs/pads ----------
  {
    auto repack = [&](size_t dst, const float* src, int rows, int sstride, int soff) {
      for (int t = gtid; t < rows * HP; t += NTH) {
        int r = t >> 9, k = t & 511;
        wsf[dst + t] = (k < Hc) ? src[(size_t)r * sstride + soff + k] : 0.0f;
      }
    };
    repack(OFF_WG,  gatew, Hc,  Gc,  0);
    repack(OFF_WM,  mapw,  Hc,  Gc,  0);
    repack(OFF_WHH, whh,   H3c, Hc,  0);
    repack(OFF_WHV, ae1w,  H4c, H2c, 0);
    repack(OFF_WHJ, ae1w,  H4c, H2c, Hc);
    repack(OFF_WAV1,av1w,  H2c, Hc,  0);
    // gi_all[b][idx][r] = w_ih@x_t + b_ih
    for (int t = gtid; t < Bc * Sc * H3c; t += NTH) {
      int r = t % H3c, bi = t / H3c;
      float acc = bih[r];
      const float* x = enc + (size_t)bi * Cc;
      const float* w = wih + (size_t)r * Cc;
      #pragma unroll
      for (int c = 0; c < Cc; ++c) acc = fmaf(w[c], x[c], acc);
      wsf[OFF_GI + (size_t)bi * 1536 + r] = acc;
    }
    // gs0 = lin1(z)  (zero pads)
    for (int t = gtid; t < Bc * HP; t += NTH) {
      int b = t >> 9, i = t & 511;
      float v = 0.0f;
      if (i < Hc) {
        float acc = lin1b[i];
        const float* zz = z + (size_t)b * LATc;
        const float* w  = lin1w + (size_t)i * LATc;
        for (int k = 0; k < LATc; ++k) acc = fmaf(w[k], zz[k], acc);
        v = acc;
      }
      wsf[OFF_GS0 + t] = v;
    }
    // zero gen_dep + node region (bypass stores: no dirty L2 lines anywhere)
    for (int t = gtid; t < 6656; t += NTH) stg(a.out + t, 0.0f);
    // zero pads (k in [501,512)) of every hv_seq slot (they get multiplied by zero weights,
    // but must be finite)
    for (int t = gtid; t < Bc * Sc * 16; t += NTH)
      for (int k = Hc; k < HP; ++k) stg(wsf + OFF_HSEQ + (size_t)t * HP + k, 0.0f);
  }
  gbar(bar, barid, true);   // heavy: flush constants to LLC

  // ---------- stage 2: gh = W_hh @ h, GRU elementwise -> hv_seq[b][index][dsts] ----------
  // mapping: bq=blk>>6 (4 batches each), icc=blk&63 (8 i's each); thread=(i8,bb,l)
  auto stage2 = [&](const float* hsrc /*[B][512]*/, int index, int dsts) {
    int bq = blk >> 6, icc = blk & 63;
    {
      const float4* src = reinterpret_cast<const float4*>(hsrc + (size_t)bq * 2048);
      float4* d = reinterpret_cast<float4*>(lds_h);
      for (int t = tid; t < 512; t += NTHR) d[t] = src[t];
    }
    __syncthreads();
    int i8 = tid >> 5, bb = (tid >> 3) & 3, l = tid & 7;
    int i = icc * 8 + i8, b = bq * 4 + bb;
    if (i < Hc) {
      const float4* hb = reinterpret_cast<const float4*>(lds_h + bb * 512);
      const float4* w0 = reinterpret_cast<const float4*>(wsf + OFF_WHH + (size_t)i * HP);
      const float4* w1 = reinterpret_cast<const float4*>(wsf + OFF_WHH + (size_t)(Hc + i) * HP);
      const float4* w2 = reinterpret_cast<const float4*>(wsf + OFF_WHH + (size_t)(2 * Hc + i) * HP);
      float gr = 0.f, gz = 0.f, gn = 0.f;
      #pragma unroll
      for (int s2 = 0; s2 < 16; ++s2) {
        int k4 = s2 * 8 + l;
        float4 hv4 = hb[k4];
        float4 a0 = w0[k4], a1 = w1[k4], a2 = w2[k4];
        gr = fmaf(a0.x, hv4.x, gr); gr = fmaf(a0.y, hv4.y, gr); gr = fmaf(a0.z, hv4.z, gr); gr = fmaf(a0.w, hv4.w, gr);
        gz = fmaf(a1.x, hv4.x, gz); gz = fmaf(a1.y, hv4.y, gz); gz = fmaf(a1.z, hv4.z, gz); gz = fmaf(a1.w, hv4.w, gz);
        gn = fmaf(a2.x, hv4.x, gn); gn = fmaf(a2.y, hv4.y, gn); gn = fmaf(a2.z, hv4.z, gn); gn = fmaf(a2.w, hv4.w, gn);
      }
      gr += __shfl_xor(gr, 1); gr += __shfl_xor(gr, 2); gr += __shfl_xor(gr, 4);
      gz += __shfl_xor(gz, 1); gz += __shfl_xor(gz, 2); gz += __shfl_xor(gz, 4);
      gn += __shfl_xor(gn, 1); gn += __shfl_xor(gn, 2); gn += __shfl_xor(gn, 4);
      if (l == 0) {
        const float* gi = wsf + OFF_GI + ((size_t)b * 16 + index) * 1536;
        float rr = sigf(gi[i] + gr + bhh[i]);
        float uu = sigf(gi[Hc + i] + gz + bhh[Hc + i]);
        float nn = tanhf_(gi[2 * Hc + i] + rr * (gn + bhh[2 * Hc + i]));
        float h  = lds_h[bb * 512 + i];
        stg(wsf + hslot(b, index, dsts) + i, (1.0f - uu) * nn + uu * h);
      }
    }
  };

  // ---------- main sequential phase ----------
  for (int index = 0; index < Sc; ++index) {
    // phase X1
    if (index == 0) {
      stage2(wsf + OFF_GS0, 0, 0);          // hv = gru(x_0, graph_state)
    } else {
      int b = blk >> 4, ic = blk & 15;
      int il = tid >> 3, l = tid & 7;
      int i = ic * 32 + il;
      { // load hvp = final hv of index-1
        const float4* src = reinterpret_cast<const float4*>(wsf + hslot(b, index - 1, index - 1));
        float4* d = reinterpret_cast<float4*>(lds_h);
        for (int t = tid; t < 128; t += NTHR) d[t] = src[t];
      }
      __syncthreads();
      if (i < Hc) {
        const float4* wq4 = reinterpret_cast<const float4*>(wsf + OFF_WG + (size_t)i * HP);
        const float4* wm4 = reinterpret_cast<const float4*>(wsf + OFF_WM + (size_t)i * HP);
        const float4* hb4 = reinterpret_cast<const float4*>(lds_h);
        float aq = 0.f, am = 0.f;
        #pragma unroll
        for (int s2 = 0; s2 < 16; ++s2) {
          int k4 = s2 * 8 + l;
          float4 hv4 = hb4[k4], w1 = wq4[k4], w2 = wm4[k4];
          aq = fmaf(w1.x, hv4.x, aq); aq = fmaf(w1.y, hv4.y, aq); aq = fmaf(w1.z, hv4.z, aq); aq = fmaf(w1.w, hv4.w, aq);
          am = fmaf(w2.x, hv4.x, am); am = fmaf(w2.y, hv4.y, am); am = fmaf(w2.z, hv4.z, am); am = fmaf(w2.w, hv4.w, am);
        }
        aq += __shfl_xor(aq, 1); aq += __shfl_xor(aq, 2); aq += __shfl_xor(aq, 4);
        am += __shfl_xor(am, 1); am += __shfl_xor(am, 2); am += __shfl_xor(am, 4);
        if (l == 0) {
          // finalize table row index-1
          stg(wsf + OFF_QTAB + ((size_t)b * 16 + (index - 1)) * HP + i, aq + gatew[(size_t)i * Gc + Hc + (index - 1)]);
          stg(wsf + OFF_MTAB + ((size_t)b * 16 + (index - 1)) * HP + i, am + mapw[(size_t)i * Gc + Hc + (index - 1)]);
          // initial hv for this index: gru(x_t, 0)
          const float* gi = wsf + OFF_GI + ((size_t)b * 16 + index) * 1536;
          float rr = sigf(gi[i] + bhh[i]);
          float uu = sigf(gi[Hc + i] + bhh[Hc + i]);
          float nn = tanhf_(gi[2 * Hc + i] + rr * bhh[2 * Hc + i]);
          stg(wsf + hslot(b, index, 0) + i, (1.0f - uu) * nn);
        }
      }
    }
    gbar(bar, barid, false);

    const int tri = index * (index - 1) / 2;
    for (int s = 0; s < index; ++s) {
      const int vj = index - 1 - s;
      // ---- stage 1: h_in = PS[vj] + f(Wg@nhs_idx, Wm@nhs_idx, a_ii) ----
      {
        int b = blk >> 4, ic = blk & 15;
        int il = tid >> 3, l = tid & 7;
        int i = ic * 32 + il;
        if (s > 0) {
          const float4* src = reinterpret_cast<const float4*>(wsf + hslot(b, index, s));
          float4* d = reinterpret_cast<float4*>(lds_h);
          for (int t = tid; t < 128; t += NTHR) d[t] = src[t];
        }
        if (s == 0 && l == 0) {
          // build PS (backward cumsum over j, excluding j==index)
          float acc = 0.f;
          bool act = (i < Hc);
          float gb = act ? gateb[i] : 0.f, mb = act ? mapb[i] : 0.f;
          const float* drow = dep + ((size_t)b * 16 + index) * 16;
          for (int j = 15; j >= 0; --j) {
            if (act && j != index) {
              float aa = drow[j];
              float q, m;
              if (j < index) {
                q = wsf[OFF_QTAB + ((size_t)b * 16 + j) * HP + i];
                m = wsf[OFF_MTAB + ((size_t)b * 16 + j) * HP + i];
              } else {
                q = gatew[(size_t)i * Gc + Hc + j];
                m = mapw [(size_t)i * Gc + Hc + j];
              }
              float sg = sigf(fmaf(aa, q, gb));
              acc = fmaf(aa * sg, fmaf(aa, m, mb), acc);
            }
            lds_ps[il * 16 + j] = acc;
          }
        }
        __syncthreads();
        float aq = 0.f, am = 0.f;
        if (s > 0 && i < Hc) {
          const float4* wq4 = reinterpret_cast<const float4*>(wsf + OFF_WG + (size_t)i * HP);
          const float4* wm4 = reinterpret_cast<const float4*>(wsf + OFF_WM + (size_t)i * HP);
          const float4* hb4 = reinterpret_cast<const float4*>(lds_h);
          #pragma unroll
          for (int s2 = 0; s2 < 16; ++s2) {
            int k4 = s2 * 8 + l;
            float4 hv4 = hb4[k4], w1 = wq4[k4], w2 = wm4[k4];
            aq = fmaf(w1.x, hv4.x, aq); aq = fmaf(w1.y, hv4.y, aq); aq = fmaf(w1.z, hv4.z, aq); aq = fmaf(w1.w, hv4.w, aq);
            am = fmaf(w2.x, hv4.x, am); am = fmaf(w2.y, hv4.y, am); am = fmaf(w2.z, hv4.z, am); am = fmaf(w2.w, hv4.w, am);
          }
          aq += __shfl_xor(aq, 1); aq += __shfl_xor(aq, 2); aq += __shfl_xor(aq, 4);
          am += __shfl_xor(am, 1); am += __shfl_xor(am, 2); am += __shfl_xor(am, 4);
        }
        if (l == 0) {
          float* hdst = wsf + OFF_HINS + (size_t)(tri + s) * Bc * HP + (size_t)b * HP;
          if (i < Hc) {
            float gb = gateb[i], mb = mapb[i];
            float aI = dep[((size_t)b * 16 + index) * 16 + index];
            float Qi = aq + gatew[(size_t)i * Gc + Hc + index];
            float Mi = am + mapw [(size_t)i * Gc + Hc + index];
            float f  = aI * sigf(fmaf(aI, Qi, gb)) * fmaf(aI, Mi, mb);
            stg(hdst + i, lds_ps[il * 16 + vj] + f);
          } else {
            stg(hdst + i, 0.0f);
          }
        }
      }
      gbar(bar, barid, false);
      // ---- stage 2 ----
      stage2(wsf + OFF_HINS + (size_t)(tri + s) * Bc * HP, index, s + 1);
      gbar(bar, barid, false);
    }
  }

  // ---------- F1: Bhj = W_hj @ nhs_j  and  tbuf = relu(av1 @ gs) ----------
  {
    int b = blk >> 4, rs = blk & 15;
    int il = tid >> 3, l = tid & 7;
    // --- Bhj: 15 nhs vectors in LDS (row 15 zero), rows slice [rs*126, +126) ---
    for (int t = tid; t < 16 * 128; t += NTHR) {
      int j = t >> 7, k4 = t & 127;
      float4 v = {0.f, 0.f, 0.f, 0.f};
      if (j < 15) v = reinterpret_cast<const float4*>(wsf + hslot(b, j, j))[k4];
      reinterpret_cast<float4*>(lds_h)[t] = v;
    }
    __syncthreads();
    for (int half = 0; half < 2; ++half) {
      int jbase = half * 8;
      float acc[4][8];
      #pragma unroll
      for (int q = 0; q < 4; ++q)
        #pragma unroll
        for (int j = 0; j < 8; ++j) acc[q][j] = 0.f;
      int rbase = rs * 126 + il * 4;
      #pragma unroll
      for (int s2 = 0; s2 < 16; ++s2) {
        int k4 = s2 * 8 + l;
        float4 h4[8];
        #pragma unroll
        for (int j = 0; j < 8; ++j) h4[j] = reinterpret_cast<float4*>(lds_h)[(jbase + j) * 128 + k4];
        #pragma unroll
        for (int q = 0; q < 4; ++q) {
          float4 wv = reinterpret_cast<const float4*>(wsf + OFF_WHJ)[(size_t)(rbase + q) * 128 + k4];
          #pragma unroll
          for (int j = 0; j < 8; ++j) {
            acc[q][j] = fmaf(wv.x, h4[j].x, acc[q][j]); acc[q][j] = fmaf(wv.y, h4[j].y, acc[q][j]);
            acc[q][j] = fmaf(wv.z, h4[j].z, acc[q][j]); acc[q][j] = fmaf(wv.w, h4[j].w, acc[q][j]);
          }
        }
      }
      #pragma unroll
      for (int q = 0; q < 4; ++q) {
        int r = rbase + q;
        bool rowok = (il * 4 + q < 126) && (r < H4c);
        #pragma unroll
        for (int j = 0; j < 8; ++j) {
          float v = acc[q][j];
          v += __shfl_xor(v, 1); v += __shfl_xor(v, 2); v += __shfl_xor(v, 4);
          if (l == 0 && rowok && (jbase + j) < 15)
            stg(wsf + OFF_BHJ + ((size_t)b * 15 + jbase + j) * 2048 + r, v);
        }
      }
    }
    __syncthreads();
    // --- tbuf: 16 graph-state vectors in LDS, rows slice of av1 (63 rows) ---
    for (int t = tid; t < 16 * 128; t += NTHR) {
      int idx = t >> 7, k4 = t & 127;
      const float4* src = (idx == 0)
        ? reinterpret_cast<const float4*>(wsf + OFF_GS0 + (size_t)b * HP)
        : reinterpret_cast<const float4*>(wsf + hslot(b, idx - 1, idx - 1));
      reinterpret_cast<float4*>(lds_h)[t] = src[k4];
    }
    __syncthreads();
    for (int half = 0; half < 2; ++half) {
      int jbase = half * 8;
      float acc[2][8];
      #pragma unroll
      for (int q = 0; q < 2; ++q)
        #pragma unroll
        for (int j = 0; j < 8; ++j) acc[q][j] = 0.f;
      int rbase = rs * 63 + il * 2;
      #pragma unroll
      for (int s2 = 0; s2 < 16; ++s2) {
        int k4 = s2 * 8 + l;
        float4 h4[8];
        #pragma unroll
        for (int j = 0; j < 8; ++j) h4[j] = reinterpret_cast<float4*>(lds_h)[(jbase + j) * 128 + k4];
        #pragma unroll
        for (int q = 0; q < 2; ++q) {
          float4 wv = reinterpret_cast<const float4*>(wsf + OFF_WAV1)[(size_t)(rbase + q) * 128 + k4];
          #pragma unroll
          for (int j = 0; j < 8; ++j) {
            acc[q][j] = fmaf(wv.x, h4[j].x, acc[q][j]); acc[q][j] = fmaf(wv.y, h4[j].y, acc[q][j]);
            acc[q][j] = fmaf(wv.z, h4[j].z, acc[q][j]); acc[q][j] = fmaf(wv.w, h4[j].w, acc[q][j]);
          }
        }
      }
      #pragma unroll
      for (int q = 0; q < 2; ++q) {
        int r = rbase + q;
        bool rowok = (il * 2 + q < 63) && (r < H2c);
        float b1 = rowok ? av1b[r] : 0.f;
        #pragma unroll
        for (int j = 0; j < 8; ++j) {
          float v = acc[q][j];
          v += __shfl_xor(v, 1); v += __shfl_xor(v, 2); v += __shfl_xor(v, 4);
          if (l == 0 && rowok)
            stg(wsf + OFF_TBUF + ((size_t)b * 16 + jbase + j) * 1024 + r, fmaxf(v + b1, 0.f));
        }
      }
    }
  }
  gbar(bar, barid, false);

  // ---------- F2: all edges (120 per batch) + gen_node_encoding ----------
  {
    int b = blk >> 4, rs = blk & 15;
    int il = tid >> 3, l = tid & 7;
    for (int chunk = 0; chunk < 15; ++chunk) {
      // decode this chunk's 8 tasks
      int idxs[8], vjs[8]; bool tval[8];
      #pragma unroll
      for (int j = 0; j < 8; ++j) {
        int e = chunk * 8 + j;
        if (e < 120) {
          int ix = 1, rem = e;
          while (rem >= ix) { rem -= ix; ++ix; }
          idxs[j] = ix; vjs[j] = rem; tval[j] = true;
        } else { idxs[j] = 1; vjs[j] = 0; tval[j] = false; }
      }
      __syncthreads();
      for (int t = tid; t < 8 * 128; t += NTHR) {
        int sl = t >> 7, k4 = t & 127;
        int sE = idxs[sl] - 1 - vjs[sl];
        reinterpret_cast<float4*>(lds_h)[t] =
          reinterpret_cast<const float4*>(wsf + hslot(b, idxs[sl], sE))[k4];
      }
      __syncthreads();
      float part[8];
      #pragma unroll
      for (int j = 0; j < 8; ++j) part[j] = 0.f;
      int rbase = rs * 126 + il * 4;
      float acc[4][8];
      #pragma unroll
      for (int q = 0; q < 4; ++q)
        #pragma unroll
        for (int j = 0; j < 8; ++j) acc[q][j] = 0.f;
      #pragma unroll
      for (int s2 = 0; s2 < 16; ++s2) {
        int k4 = s2 * 8 + l;
        float4 h4[8];
        #pragma unroll
        for (int j = 0; j < 8; ++j) h4[j] = reinterpret_cast<float4*>(lds_h)[j * 128 + k4];
        #pragma unroll
        for (int q = 0; q < 4; ++q) {
          float4 wv = reinterpret_cast<const float4*>(wsf + OFF_WHV)[(size_t)(rbase + q) * 128 + k4];
          #pragma unroll
          for (int j = 0; j < 8; ++j) {
            acc[q][j] = fmaf(wv.x, h4[j].x, acc[q][j]); acc[q][j] = fmaf(wv.y, h4[j].y, acc[q][j]);
            acc[q][j] = fmaf(wv.z, h4[j].z, acc[q][j]); acc[q][j] = fmaf(wv.w, h4[j].w, acc[q][j]);
          }
        }
      }
      #pragma unroll
      for (int q = 0; q < 4; ++q) {
        int r = rbase + q;
        bool rowok = (il * 4 + q < 126) && (r < H4c);
        float aer = rowok ? ae2w[r] : 0.f;
        float b1r = rowok ? ae1b[r] : 0.f;
        #pragma unroll
        for (int j = 0; j < 8; ++j) {
          float v = acc[q][j];
          v += __shfl_xor(v, 1); v += __shfl_xor(v, 2); v += __shfl_xor(v, 4);
          if (l == 0 && rowok && tval[j]) {
            float bh = wsf[OFF_BHJ + ((size_t)b * 15 + vjs[j]) * 2048 + r];
            part[j] = fmaf(aer, fmaxf(v + bh + b1r, 0.f), part[j]);
          }
        }
      }
      if (l == 0) {
        #pragma unroll
        for (int j = 0; j < 8; ++j) lds_red[il * 8 + j] = part[j];
      }
      __syncthreads();
      if (tid < 8) {
        float v = 0.f;
        for (int g = 0; g < 32; ++g) v += lds_red[g * 8 + tid];
        if (rs == 0) v += ae2b[0];
        if (tval[tid])
          atomicAdd(a.out + ((size_t)b * 16 + idxs[tid]) * 16 + vjs[tid], v);
      }
      __syncthreads();
    }
    // gen_node_encoding: (b, idx) per block
    {
      int bo = blk >> 4, idx = blk & 15;
      const float* tb = wsf + OFF_TBUF + ((size_t)bo * 16 + idx) * 1024;
      float accn[10];
      #pragma unroll
      for (int c = 0; c < 10; ++c) accn[c] = 0.f;
      for (int r = tid; r < H2c; r += NTHR) {
        float tv = tb[r];
        #pragma unroll
        for (int c = 0; c < 10; ++c) accn[c] = fmaf(av2w[(size_t)c * H2c + r], tv, accn[c]);
      }
      #pragma unroll
      for (int c = 0; c < 10; ++c) {
        float v = accn[c];
        for (int m2 = 1; m2 < 64; m2 <<= 1) v += __shfl_xor(v, m2);
        if ((tid & 63) == 0) lds_red[(tid >> 6) * 10 + c] = v;
      }
      __syncthreads();
      if (tid == 0) {
        for (int c = 0; c < 10; ++c) {
          float v = av2b[c] + lds_red[c] + lds_red[10 + c] + lds_red[20 + c] + lds_red[30 + c];
          stg(a.out + 4096 + ((size_t)bo * 16 + idx) * 10 + c, v);
        }
      }
    }
  }
}

extern "C" void kernel_launch(void* const* d_in, const int* in_sizes, int n_in,
                              void* d_out, int out_size, void* d_ws, size_t ws_size,
                              hipStream_t stream) {
  (void)in_sizes; (void)n_in; (void)out_size;
  if (ws_size < WS_BYTES_NEEDED) return;  // fail loudly via validation rather than corrupt memory
  KArgs a;
  for (int i = 0; i < 21; ++i) a.in[i] = (const float*)d_in[i];
  a.out = (float*)d_out;
  a.wsf = (float*)d_ws;
  a.bar = (unsigned*)((char*)d_ws + WS_FLOATS * 4);
  Decoder_20014547599839_kernel<<<NBLK, NTHR, 0, stream>>>(a);
}

// Round 3
// 3743.278 us; speedup vs baseline: 1.3329x; 1.3329x over previous
//
#include <hip/hip_runtime.h>

#define DEVFN static __device__ __forceinline__

namespace {
constexpr int Hc = 501, Gc = 517;
// ---- workspace float offsets ----
constexpr size_t OFF_WGP = 0;                               // [512][512] gate_w[:, :H] padded
constexpr size_t OFF_WMP = OFF_WGP + (size_t)512 * 512;     // map_w[:, :H]
constexpr size_t OFF_WHP = OFF_WMP + (size_t)512 * 512;     // w_hh packed [i][3][512]
constexpr size_t OFF_WHV = OFF_WHP + (size_t)512 * 1536;    // ae1_w[:, :H]  [2048][512]
constexpr size_t OFF_WHJ = OFF_WHV + (size_t)2048 * 512;    // ae1_w[:, H:]  [2048][512]
constexpr size_t OFF_WAV = OFF_WHJ + (size_t)2048 * 512;    // av1_w [1024][512]
constexpr size_t OFF_GCOL= OFF_WAV + (size_t)1024 * 512;    // gate_w[:, H+j] [512][16]
constexpr size_t OFF_MCOL= OFF_GCOL + (size_t)512 * 16;
constexpr size_t OFF_GI  = OFF_MCOL + (size_t)512 * 16;     // [16][16][1536]
constexpr size_t OFF_GS0 = OFF_GI  + (size_t)16 * 16 * 1536;// [16][512]
constexpr size_t OFF_HSEQ= OFF_GS0 + (size_t)16 * 512;      // [16 b][136 slot][512]
constexpr size_t OFF_HINS= OFF_HSEQ+ (size_t)16 * 136 * 512;// [120 slot][16 b][512]
constexpr size_t OFF_TBUF= OFF_HINS+ (size_t)120 * 16 * 512;// [16 b][16 idx][1024]
constexpr size_t WS_FLOATS=OFF_TBUF+ (size_t)16 * 16 * 1024;
constexpr size_t N_FLG   = (size_t)8 * 256 * 32;            // [group][pid][member]
constexpr size_t WS_NEED = (WS_FLOATS + N_FLG + 256 + 64) * 4;

// ---- LDS float offsets ----
constexpr int SM_WHH = 0;       // 16*3*512 = 24576
constexpr int SM_ST  = 24576;   // 2*512 staging
constexpr int SM_QM  = 25600;   // [b][q/m][j<15][ig]  2*2*15*16 = 960
constexpr int SM_PS  = 26560;   // [b][ig][vj] 512
constexpr int SM_GC  = 27072;   // [q/m][ig][j] 512
constexpr int SM_GIL = 27584;   // [b][r][ig] 96
constexpr int SM_BHH = 27680;   // [r][ig] 48
constexpr int SM_GB  = 27728;   // 16
constexpr int SM_MB  = 27744;   // 16
constexpr int SM_DEP = 27760;   // [b][j] 32
constexpr int SM_TOT = 27792;
// F-phase reuse (whh region dead after scan)
constexpr int SM_BHJ = 8192;    // [j<15][128]
constexpr int SM_RED = 10112;   // 260
} // namespace

DEVFN float sigf(float x)  { return 1.0f / (1.0f + __expf(-x)); }
DEVFN float tanhf_(float x){ float e2 = __expf(2.0f * x); return 1.0f - 2.0f / (e2 + 1.0f); }
DEVFN void  stgf(float* p, float v) { __hip_atomic_store(p, v, __ATOMIC_RELAXED, __HIP_MEMORY_SCOPE_AGENT); }
DEVFN size_t hslotf(int b, int slot) { return OFF_HSEQ + ((size_t)b * 136 + slot) * 512; }
DEVFN int trif(int idx) { return idx * (idx + 1) / 2; }

struct KArgs {
  const float* in[21];
  float* out;
  float* wsf;
};

// ================= init kernel: repack weights, gi, gs0, zero out/flags ==========
__global__ __launch_bounds__(256) void k0_init(KArgs a) {
  const float* z    = a.in[0];  const float* enc  = a.in[2];
  const float* lin1w= a.in[3];  const float* lin1b= a.in[4];
  const float* av1w = a.in[5];
  const float* ae1w = a.in[9];
  const float* gatew= a.in[13]; const float* mapw = a.in[15];
  const float* wih  = a.in[17]; const float* bih  = a.in[18];
  const float* whh  = a.in[19];
  float* wsf = a.wsf;
  const int gtid = blockIdx.x * 256 + threadIdx.x;
  const int NTH = 256 * 256;

  for (size_t t = gtid; t < (size_t)512 * 512; t += NTH) {
    int i = t >> 9, k = t & 511;
    bool ok = (i < Hc && k < Hc);
    wsf[OFF_WGP + t] = ok ? gatew[(size_t)i * Gc + k] : 0.f;
    wsf[OFF_WMP + t] = ok ? mapw [(size_t)i * Gc + k] : 0.f;
  }
  for (size_t t = gtid; t < (size_t)512 * 1536; t += NTH) {
    int i = t / 1536, rk = t % 1536, r = rk >> 9, k = rk & 511;
    wsf[OFF_WHP + t] = (i < Hc && k < Hc) ? whh[((size_t)r * Hc + i) * Hc + k] : 0.f;
  }
  for (size_t t = gtid; t < (size_t)2048 * 512; t += NTH) {
    int r = t >> 9, k = t & 511;
    bool ok = (r < 2004 && k < Hc);
    wsf[OFF_WHV + t] = ok ? ae1w[(size_t)r * 1002 + k]      : 0.f;
    wsf[OFF_WHJ + t] = ok ? ae1w[(size_t)r * 1002 + Hc + k] : 0.f;
  }
  for (size_t t = gtid; t < (size_t)1024 * 512; t += NTH) {
    int r = t >> 9, k = t & 511;
    wsf[OFF_WAV + t] = (r < 1002 && k < Hc) ? av1w[(size_t)r * Hc + k] : 0.f;
  }
  for (size_t t = gtid; t < (size_t)512 * 16; t += NTH) {
    int i = t >> 4, j = t & 15;
    wsf[OFF_GCOL + t] = (i < Hc) ? gatew[(size_t)i * Gc + Hc + j] : 0.f;
    wsf[OFF_MCOL + t] = (i < Hc) ? mapw [(size_t)i * Gc + Hc + j] : 0.f;
  }
  for (size_t t = gtid; t < (size_t)16 * 16 * 1503; t += NTH) {
    int r = t % 1503; size_t bi = t / 1503;
    float acc = bih[r];
    const float* x = enc + bi * 10;
    const float* w = wih + (size_t)r * 10;
    #pragma unroll
    for (int c = 0; c < 10; ++c) acc = fmaf(w[c], x[c], acc);
    wsf[OFF_GI + bi * 1536 + r] = acc;
  }
  for (size_t t = gtid; t < (size_t)16 * 512; t += NTH) {
    int b = t >> 9, i = t & 511;
    float v = 0.f;
    if (i < Hc) {
      float acc = lin1b[i];
      const float* zz = z + (size_t)b * 56;
      const float* w  = lin1w + (size_t)i * 56;
      for (int k = 0; k < 56; ++k) acc = fmaf(w[k], zz[k], acc);
      v = acc;
    }
    wsf[OFF_GS0 + t] = v;
  }
  for (size_t t = gtid; t < 4096; t += NTH) a.out[t] = 0.f;   // gen_dep zero (atomics)
  unsigned* FLG = (unsigned*)a.wsf + WS_FLOATS;
  for (size_t t = gtid; t < N_FLG + 256; t += NTH) FLG[t] = 0u;
}

// ================= main persistent kernel ==========
__global__ __launch_bounds__(256, 1) void k1_main(KArgs a) {
  const int blk = blockIdx.x, tid = threadIdx.x;
  const int g = blk >> 5, m = blk & 31;        // group (2 batches), member
  const int ig = tid >> 4, l = tid & 15;       // i-subgroup, k-lane
  const int i = m * 16 + ig;                   // owned row
  float* wsf = a.wsf;
  unsigned* FLG = (unsigned*)a.wsf + WS_FLOATS;
  unsigned* F1F = FLG + N_FLG;
  const float* dep  = a.in[1];
  const float* gateb= a.in[14]; const float* mapb = a.in[16];
  const float* bhh  = a.in[20];

  __shared__ float smem[SM_TOT];
  int pid = 0;

  // ---- persistent loads: Whh slice -> LDS; Wg/Wm slice -> VGPRs; small tables ----
  {
    float4* d = (float4*)smem;
    const float4* s = ((const float4*)(wsf + OFF_WHP)) + (size_t)m * 6144;
    for (int t = tid; t < 6144; t += 256) d[t] = s[t];
    for (int t = tid; t < 512; t += 256) {
      int q = t >> 8, r2 = t & 255, ii = r2 >> 4, j = r2 & 15;
      smem[SM_GC + t] = wsf[(q ? OFF_MCOL : OFF_GCOL) + (size_t)(m * 16 + ii) * 16 + j];
    }
    if (tid < 16) {
      int iG = m * 16 + tid;
      smem[SM_GB + tid] = (iG < Hc) ? gateb[iG] : 0.f;
      smem[SM_MB + tid] = (iG < Hc) ? mapb[iG]  : 0.f;
    }
    if (tid < 48) {
      int r = tid >> 4, ii = tid & 15, iG = m * 16 + ii;
      smem[SM_BHH + tid] = (iG < Hc) ? bhh[r * Hc + iG] : 0.f;
    }
  }
  float4 wgr[8], wmr[8];
  {
    const float4* pg = ((const float4*)(wsf + OFF_WGP)) + (size_t)i * 128;
    const float4* pm = ((const float4*)(wsf + OFF_WMP)) + (size_t)i * 128;
    #pragma unroll
    for (int t = 0; t < 8; ++t) { wgr[t] = pg[l * 8 + t]; wmr[t] = pm[l * 8 + t]; }
  }
  __syncthreads();

  // ---- group barrier: 32 parallel sentinel stores, poll 2 lines ----
  auto flagbar = [&]() {
    __syncthreads();    // drains this block's vmem before flag store
    if (tid == 0)
      __hip_atomic_store(FLG + ((size_t)g * 256 + pid) * 32 + m, (unsigned)(pid + 1),
                         __ATOMIC_RELEASE, __HIP_MEMORY_SCOPE_AGENT);
    if (tid < 64) {
      unsigned* p = FLG + ((size_t)g * 256 + pid) * 32 + (tid & 31);
      while (__hip_atomic_load(p, __ATOMIC_RELAXED, __HIP_MEMORY_SCOPE_AGENT) != (unsigned)(pid + 1))
        __builtin_amdgcn_s_sleep(2);
    }
    __syncthreads();
    ++pid;
  };

  auto stage2v = [&](size_t o0, size_t o1) {   // load 2 h-vectors (b0,b1) into LDS
    float4* d = (float4*)(smem + SM_ST);
    if (tid < 128) d[tid] = ((const float4*)(wsf + o0))[tid];
    else           d[tid] = ((const float4*)(wsf + o1))[tid - 128];
  };
  auto stagegi = [&](int index) {
    if (tid >= 64 && tid < 160) {
      int t = tid - 64, b = t / 48, r = (t / 16) % 3, ii = t & 15, iG = m * 16 + ii;
      smem[SM_GIL + (b * 3 + r) * 16 + ii] =
        (iG < Hc) ? wsf[OFF_GI + ((size_t)(2 * g + b) * 16 + index) * 1536 + (size_t)r * Hc + iG] : 0.f;
    }
  };
  auto s1dot = [&](int b, float& aq, float& am) {   // Wg/Wm row-i dot lds_st[b]
    const float4* h4 = (const float4*)(smem + SM_ST + b * 512);
    float q = 0.f, mm = 0.f;
    #pragma unroll
    for (int t = 0; t < 8; ++t) {
      float4 hv = h4[l * 8 + t];
      q = fmaf(wgr[t].x, hv.x, q); q = fmaf(wgr[t].y, hv.y, q);
      q = fmaf(wgr[t].z, hv.z, q); q = fmaf(wgr[t].w, hv.w, q);
      mm = fmaf(wmr[t].x, hv.x, mm); mm = fmaf(wmr[t].y, hv.y, mm);
      mm = fmaf(wmr[t].z, hv.z, mm); mm = fmaf(wmr[t].w, hv.w, mm);
    }
    q += __shfl_xor(q, 1); q += __shfl_xor(q, 2); q += __shfl_xor(q, 4); q += __shfl_xor(q, 8);
    mm += __shfl_xor(mm, 1); mm += __shfl_xor(mm, 2); mm += __shfl_xor(mm, 4); mm += __shfl_xor(mm, 8);
    aq = q; am = mm;
  };
  auto s2core = [&](int dstSlot) {   // gh = Whh@lds_st, GRU elementwise, store hv slice
    const float4* W = ((const float4*)smem) + ig * 384;
    for (int b = 0; b < 2; ++b) {
      const float4* h4 = (const float4*)(smem + SM_ST + b * 512);
      float gr = 0.f, gz = 0.f, gn = 0.f;
      #pragma unroll
      for (int t = 0; t < 8; ++t) {
        float4 hv = h4[l * 8 + t];
        float4 a0 = W[l * 8 + t], a1 = W[128 + l * 8 + t], a2 = W[256 + l * 8 + t];
        gr = fmaf(a0.x, hv.x, gr); gr = fmaf(a0.y, hv.y, gr); gr = fmaf(a0.z, hv.z, gr); gr = fmaf(a0.w, hv.w, gr);
        gz = fmaf(a1.x, hv.x, gz); gz = fmaf(a1.y, hv.y, gz); gz = fmaf(a1.z, hv.z, gz); gz = fmaf(a1.w, hv.w, gz);
        gn = fmaf(a2.x, hv.x, gn); gn = fmaf(a2.y, hv.y, gn); gn = fmaf(a2.z, hv.z, gn); gn = fmaf(a2.w, hv.w, gn);
      }
      gr += __shfl_xor(gr, 1); gr += __shfl_xor(gr, 2); gr += __shfl_xor(gr, 4); gr += __shfl_xor(gr, 8);
      gz += __shfl_xor(gz, 1); gz += __shfl_xor(gz, 2); gz += __shfl_xor(gz, 4); gz += __shfl_xor(gz, 8);
      gn += __shfl_xor(gn, 1); gn += __shfl_xor(gn, 2); gn += __shfl_xor(gn, 4); gn += __shfl_xor(gn, 8);
      if (l == 0) {
        // GRU leak term: h is the GRU hidden INPUT (the staged h_in), not the previous hv.
        float h  = smem[SM_ST + b * 512 + i];
        float rr = sigf(smem[SM_GIL + (b * 3 + 0) * 16 + ig] + gr + smem[SM_BHH + 0 + ig]);
        float uu = sigf(smem[SM_GIL + (b * 3 + 1) * 16 + ig] + gz + smem[SM_BHH + 16 + ig]);
        float nn = tanhf_(smem[SM_GIL + (b * 3 + 2) * 16 + ig] + rr * (gn + smem[SM_BHH + 32 + ig]));
        float v = (1.f - uu) * nn + uu * h;
        if (i >= Hc) v = 0.f;
        stgf(wsf + hslotf(2 * g + b, dstSlot) + i, v);
      }
    }
  };

  // ================= phase 0: hv(idx0) = GRU(x0, gs0) =================
  stage2v(OFF_GS0 + (size_t)(2 * g) * 512, OFF_GS0 + (size_t)(2 * g + 1) * 512);
  stagegi(0);
  __syncthreads();
  s2core(0);
  flagbar();

  // ================= scan =================
  for (int index = 1; index < 16; ++index) {
    // ---- phase A: QM-finalize(index-1), PS build, hv0, h_in(s=0) ----
    stage2v(hslotf(2 * g,     trif(index - 1) + index - 1),
            hslotf(2 * g + 1, trif(index - 1) + index - 1));
    if (tid < 32) {
      int b = tid >> 4, j = tid & 15;
      smem[SM_DEP + b * 16 + j] = dep[((size_t)(2 * g + b) * 16 + index) * 16 + j];
    }
    stagegi(index);
    __syncthreads();
    for (int b = 0; b < 2; ++b) {
      float aq, am; s1dot(b, aq, am);
      if (l == 0) {
        smem[SM_QM + ((b * 2 + 0) * 15 + (index - 1)) * 16 + ig] = aq + smem[SM_GC + ig * 16 + (index - 1)];
        smem[SM_QM + ((b * 2 + 1) * 15 + (index - 1)) * 16 + ig] = am + smem[SM_GC + 256 + ig * 16 + (index - 1)];
      }
    }
    __syncthreads();
    if (l < 2) {               // PS backward cumsum, b = l
      float acc = 0.f, gb = smem[SM_GB + ig], mb = smem[SM_MB + ig];
      for (int j = 15; j >= 0; --j) {
        if (j != index) {
          float aa = smem[SM_DEP + l * 16 + j];
          float q, mm;
          if (j < index) { q = smem[SM_QM + ((l * 2 + 0) * 15 + j) * 16 + ig];
                           mm = smem[SM_QM + ((l * 2 + 1) * 15 + j) * 16 + ig]; }
          else           { q = smem[SM_GC + ig * 16 + j];
                           mm = smem[SM_GC + 256 + ig * 16 + j]; }
          float sg = sigf(fmaf(aa, q, gb));
          acc = fmaf(aa * sg, fmaf(aa, mm, mb), acc);
        }
        smem[SM_PS + (l * 16 + ig) * 16 + j] = acc;
      }
    } else if (l < 4) {        // hv0 = gru(x,0), b = l-2
      int b = l - 2;
      float rr = sigf(smem[SM_GIL + (b * 3 + 0) * 16 + ig] + smem[SM_BHH + 0 + ig]);
      float uu = sigf(smem[SM_GIL + (b * 3 + 1) * 16 + ig] + smem[SM_BHH + 16 + ig]);
      float nn = tanhf_(smem[SM_GIL + (b * 3 + 2) * 16 + ig] + rr * smem[SM_BHH + 32 + ig]);
      float v = (1.f - uu) * nn;
      if (i >= Hc) v = 0.f;
      stgf(wsf + hslotf(2 * g + b, trif(index) + 0) + i, v);
    }
    __syncthreads();
    if (l < 2) {               // h_in(s=0): row-index term has ZERO hidden (nhs[:,index]=0)
      int b = l;
      float gb = smem[SM_GB + ig], mb = smem[SM_MB + ig];
      float aI = smem[SM_DEP + b * 16 + index];
      float Qi = smem[SM_GC + ig * 16 + index], Mi = smem[SM_GC + 256 + ig * 16 + index];
      float f = aI * sigf(fmaf(aI, Qi, gb)) * fmaf(aI, Mi, mb);
      float v = smem[SM_PS + (b * 16 + ig) * 16 + (index - 1)] + f;
      if (i >= Hc) v = 0.f;
      stgf(wsf + OFF_HINS + ((size_t)(index * (index - 1) / 2 + 0) * 16 + (2 * g + b)) * 512 + i, v);
    }
    flagbar();

    for (int s = 0; s < index; ++s) {
      // ---- S2(s): hv_{s+1} = GRU(x, h_in_s) ----
      stage2v(OFF_HINS + ((size_t)(index * (index - 1) / 2 + s) * 16 + (2 * g + 0)) * 512,
              OFF_HINS + ((size_t)(index * (index - 1) / 2 + s) * 16 + (2 * g + 1)) * 512);
      __syncthreads();
      s2core(trif(index) + s + 1);
      flagbar();
      if (s + 1 < index) {
        // ---- S1(s+1): h_in = PS[vj] + f(Wg/Wm @ hv_{s+1}) ----
        int ss = s + 1, vj = index - 1 - ss;
        stage2v(hslotf(2 * g, trif(index) + ss), hslotf(2 * g + 1, trif(index) + ss));
        __syncthreads();
        for (int b = 0; b < 2; ++b) {
          float aq, am; s1dot(b, aq, am);
          if (l == 0) {
            float gb = smem[SM_GB + ig], mb = smem[SM_MB + ig];
            float aI = smem[SM_DEP + b * 16 + index];
            float Qi = aq + smem[SM_GC + ig * 16 + index];
            float Mi = am + smem[SM_GC + 256 + ig * 16 + index];
            float f = aI * sigf(fmaf(aI, Qi, gb)) * fmaf(aI, Mi, mb);
            float v = smem[SM_PS + (b * 16 + ig) * 16 + vj] + f;
            if (i >= Hc) v = 0.f;
            stgf(wsf + OFF_HINS + ((size_t)(index * (index - 1) / 2 + ss) * 16 + (2 * g + b)) * 512 + i, v);
          }
        }
        flagbar();
      }
    }
  }

  // ================= F phases: deferred edges + node encodings =================
  {
    const int b = blk >> 4, rs = blk & 15;
    const int il = tid >> 3, l8 = tid & 7;
    float4* lds4 = (float4*)smem;
    // ---- F1a: Bhj = W_hj @ nhs_j (j<15) -> LDS ----
    __syncthreads();
    for (int t = tid; t < 2048; t += 256) {
      int j = t >> 7, k4 = t & 127;
      float4 v = {0.f, 0.f, 0.f, 0.f};
      if (j < 15) v = ((const float4*)(wsf + hslotf(b, trif(j) + j)))[k4];
      lds4[t] = v;
    }
    __syncthreads();
    for (int half = 0; half < 2; ++half) {
      int jbase = half * 8;
      float acc[4][8];
      #pragma unroll
      for (int q = 0; q < 4; ++q)
        #pragma unroll
        for (int j = 0; j < 8; ++j) acc[q][j] = 0.f;
      int rbase = rs * 126 + il * 4;
      #pragma unroll
      for (int s2 = 0; s2 < 16; ++s2) {
        int k4 = s2 * 8 + l8;
        float4 h4v[8];
        #pragma unroll
        for (int j = 0; j < 8; ++j) h4v[j] = lds4[(jbase + j) * 128 + k4];
        #pragma unroll
        for (int q = 0; q < 4; ++q) {
          float4 wv = ((const float4*)(wsf + OFF_WHJ))[(size_t)(rbase + q) * 128 + k4];
          #pragma unroll
          for (int j = 0; j < 8; ++j) {
            acc[q][j] = fmaf(wv.x, h4v[j].x, acc[q][j]); acc[q][j] = fmaf(wv.y, h4v[j].y, acc[q][j]);
            acc[q][j] = fmaf(wv.z, h4v[j].z, acc[q][j]); acc[q][j] = fmaf(wv.w, h4v[j].w, acc[q][j]);
          }
        }
      }
      #pragma unroll
      for (int q = 0; q < 4; ++q) {
        bool rowok = (il * 4 + q < 126) && (rbase + q < 2004);
        #pragma unroll
        for (int j = 0; j < 8; ++j) {
          float v = acc[q][j];
          v += __shfl_xor(v, 1); v += __shfl_xor(v, 2); v += __shfl_xor(v, 4);
          if (l8 == 0 && rowok && (jbase + j) < 15)
            smem[SM_BHJ + (jbase + j) * 128 + il * 4 + q] = v;
        }
      }
    }
    __syncthreads();
    // ---- F1b: TBUF = relu(av1 @ graph_state list) ----
    for (int t = tid; t < 2048; t += 256) {
      int idx = t >> 7, k4 = t & 127;
      const float4* src = (idx == 0)
        ? ((const float4*)(wsf + OFF_GS0 + (size_t)b * 512))
        : ((const float4*)(wsf + hslotf(b, trif(idx - 1) + idx - 1)));
      lds4[t] = src[k4];
    }
    __syncthreads();
    const float* av1b = a.in[6];
    for (int half = 0; half < 2; ++half) {
      int jbase = half * 8;
      float acc[2][8];
      #pragma unroll
      for (int q = 0; q < 2; ++q)
        #pragma unroll
        for (int j = 0; j < 8; ++j) acc[q][j] = 0.f;
      int rbase = rs * 63 + il * 2;
      #pragma unroll
      for (int s2 = 0; s2 < 16; ++s2) {
        int k4 = s2 * 8 + l8;
        float4 h4v[8];
        #pragma unroll
        for (int j = 0; j < 8; ++j) h4v[j] = lds4[(jbase + j) * 128 + k4];
        #pragma unroll
        for (int q = 0; q < 2; ++q) {
          float4 wv = ((const float4*)(wsf + OFF_WAV))[(size_t)(rbase + q) * 128 + k4];
          #pragma unroll
          for (int j = 0; j < 8; ++j) {
            acc[q][j] = fmaf(wv.x, h4v[j].x, acc[q][j]); acc[q][j] = fmaf(wv.y, h4v[j].y, acc[q][j]);
            acc[q][j] = fmaf(wv.z, h4v[j].z, acc[q][j]); acc[q][j] = fmaf(wv.w, h4v[j].w, acc[q][j]);
          }
        }
      }
      #pragma unroll
      for (int q = 0; q < 2; ++q) {
        int r = rbase + q;
        bool rowok = (il * 2 + q < 63) && (r < 1002);
        float b1 = rowok ? av1b[r] : 0.f;
        #pragma unroll
        for (int j = 0; j < 8; ++j) {
          float v = acc[q][j];
          v += __shfl_xor(v, 1); v += __shfl_xor(v, 2); v += __shfl_xor(v, 4);
          if (l8 == 0 && rowok)
            stgf(wsf + OFF_TBUF + ((size_t)b * 16 + jbase + j) * 1024 + r, fmaxf(v + b1, 0.f));
        }
      }
    }
    __syncthreads();
    if (tid == 0)
      __hip_atomic_store(F1F + b * 16 + rs, 1u, __ATOMIC_RELEASE, __HIP_MEMORY_SCOPE_AGENT);

    // ---- F2: all 120 edges per batch ----
    const float* ae1b = a.in[10]; const float* ae2w = a.in[11]; const float* ae2b = a.in[12];
    for (int chunk = 0; chunk < 15; ++chunk) {
      int idxs[8], vjs[8]; bool tval[8];
      #pragma unroll
      for (int j = 0; j < 8; ++j) {
        int e = chunk * 8 + j;
        if (e < 120) {
          int ix = 1, rem = e;
          while (rem >= ix) { rem -= ix; ++ix; }
          idxs[j] = ix; vjs[j] = rem; tval[j] = true;
        } else { idxs[j] = 1; vjs[j] = 0; tval[j] = false; }
      }
      __syncthreads();
      for (int t = tid; t < 1024; t += 256) {
        int sl = t >> 7, k4 = t & 127;
        int sE = idxs[sl] - 1 - vjs[sl];
        lds4[t] = ((const float4*)(wsf + hslotf(b, trif(idxs[sl]) + sE)))[k4];
      }
      __syncthreads();
      float part[8];
      #pragma unroll
      for (int j = 0; j < 8; ++j) part[j] = 0.f;
      int rbase = rs * 126 + il * 4;
      float acc[4][8];
      #pragma unroll
      for (int q = 0; q < 4; ++q)
        #pragma unroll
        for (int j = 0; j < 8; ++j) acc[q][j] = 0.f;
      #pragma unroll
      for (int s2 = 0; s2 < 16; ++s2) {
        int k4 = s2 * 8 + l8;
        float4 h4v[8];
        #pragma unroll
        for (int j = 0; j < 8; ++j) h4v[j] = lds4[j * 128 + k4];
        #pragma unroll
        for (int q = 0; q < 4; ++q) {
          float4 wv = ((const float4*)(wsf + OFF_WHV))[(size_t)(rbase + q) * 128 + k4];
          #pragma unroll
          for (int j = 0; j < 8; ++j) {
            acc[q][j] = fmaf(wv.x, h4v[j].x, acc[q][j]); acc[q][j] = fmaf(wv.y, h4v[j].y, acc[q][j]);
            acc[q][j] = fmaf(wv.z, h4v[j].z, acc[q][j]); acc[q][j] = fmaf(wv.w, h4v[j].w, acc[q][j]);
          }
        }
      }
      #pragma unroll
      for (int q = 0; q < 4; ++q) {
        int r = rbase + q;
        bool rowok = (il * 4 + q < 126) && (r < 2004);
        float aer = rowok ? ae2w[r] : 0.f;
        float b1r = rowok ? ae1b[r] : 0.f;
        #pragma unroll
        for (int j = 0; j < 8; ++j) {
          float v = acc[q][j];
          v += __shfl_xor(v, 1); v += __shfl_xor(v, 2); v += __shfl_xor(v, 4);
          if (l8 == 0 && rowok && tval[j]) {
            float bh = smem[SM_BHJ + vjs[j] * 128 + il * 4 + q];
            part[j] = fmaf(aer, fmaxf(v + bh + b1r, 0.f), part[j]);
          }
        }
      }
      if (l8 == 0) {
        #pragma unroll
        for (int j = 0; j < 8; ++j) smem[SM_RED + il * 8 + j] = part[j];
      }
      __syncthreads();
      if (tid < 8) {
        float v = 0.f;
        for (int q = 0; q < 32; ++q) v += smem[SM_RED + q * 8 + tid];
        if (rs == 0) v += ae2b[0];
        if (tval[tid])
          atomicAdd(a.out + ((size_t)b * 16 + idxs[tid]) * 16 + vjs[tid], v);
      }
      __syncthreads();
    }
    // ---- F3: gen_node_encoding[(b, rs)] ----
    if (tid < 16) {
      unsigned* p = F1F + b * 16 + tid;
      while (__hip_atomic_load(p, __ATOMIC_RELAXED, __HIP_MEMORY_SCOPE_AGENT) != 1u)
        __builtin_amdgcn_s_sleep(2);
    }
    __syncthreads();
    {
      const float* av2w = a.in[7]; const float* av2b = a.in[8];
      const float* tb = wsf + OFF_TBUF + ((size_t)b * 16 + rs) * 1024;
      float accn[10];
      #pragma unroll
      for (int c = 0; c < 10; ++c) accn[c] = 0.f;
      for (int r = tid; r < 1002; r += 256) {
        float tv = tb[r];
        #pragma unroll
        for (int c = 0; c < 10; ++c) accn[c] = fmaf(av2w[(size_t)c * 1002 + r], tv, accn[c]);
      }
      #pragma unroll
      for (int c = 0; c < 10; ++c) {
        float v = accn[c];
        for (int m2 = 1; m2 < 64; m2 <<= 1) v += __shfl_xor(v, m2);
        if ((tid & 63) == 0) smem[SM_RED + (tid >> 6) * 10 + c] = v;
      }
      __syncthreads();
      if (tid == 0) {
        for (int c = 0; c < 10; ++c) {
          float v = av2b[c] + smem[SM_RED + c] + smem[SM_RED + 10 + c] + smem[SM_RED + 20 + c] + smem[SM_RED + 30 + c];
          stgf(a.out + 4096 + ((size_t)b * 16 + rs) * 10 + c, v);
        }
      }
    }
  }
}

extern "C" void kernel_launch(void* const* d_in, const int* in_sizes, int n_in,
                              void* d_out, int out_size, void* d_ws, size_t ws_size,
                              hipStream_t stream) {
  (void)in_sizes; (void)n_in; (void)out_size;
  if (ws_size < WS_NEED) return;   // fail loudly via validation
  KArgs a;
  for (int k = 0; k < 21; ++k) a.in[k] = (const float*)d_in[k];
  a.out = (float*)d_out;
  a.wsf = (float*)d_ws;
  k0_init<<<256, 256, 0, stream>>>(a);
  k1_main<<<256, 256, 0, stream>>>(a);
}

// Round 4
// 3477.130 us; speedup vs baseline: 1.4349x; 1.0765x over previous
//
#include <hip/hip_runtime.h>

#define DEVFN static __device__ __forceinline__

namespace {
constexpr int Hc = 501, Gc = 517;
// ---- workspace float offsets ----
constexpr size_t OFF_WGP = 0;                               // [512][512] gate_w[:, :H] padded
constexpr size_t OFF_WMP = OFF_WGP + (size_t)512 * 512;     // map_w[:, :H]
constexpr size_t OFF_WHP = OFF_WMP + (size_t)512 * 512;     // w_hh packed [i][3][512]
constexpr size_t OFF_WHV = OFF_WHP + (size_t)512 * 1536;    // ae1_w[:, :H]  [2048][512]
constexpr size_t OFF_WHJ = OFF_WHV + (size_t)2048 * 512;    // ae1_w[:, H:]  [2048][512]
constexpr size_t OFF_WAV = OFF_WHJ + (size_t)2048 * 512;    // av1_w [1024][512]
constexpr size_t OFF_GCOL= OFF_WAV + (size_t)1024 * 512;    // gate_w[:, H+j] [512][16]
constexpr size_t OFF_MCOL= OFF_GCOL + (size_t)512 * 16;
constexpr size_t OFF_GI  = OFF_MCOL + (size_t)512 * 16;     // [16][16][1536]
constexpr size_t OFF_GS0 = OFF_GI  + (size_t)16 * 16 * 1536;// [16][512]
constexpr size_t OFF_HSEQ= OFF_GS0 + (size_t)16 * 512;      // [16 b][136 slot][512]
constexpr size_t OFF_HINS= OFF_HSEQ+ (size_t)16 * 136 * 512;// [120 slot][16 b][512]
constexpr size_t OFF_TBUF= OFF_HINS+ (size_t)120 * 16 * 512;// [16 b][16 idx][1024]
constexpr size_t WS_FLOATS=OFF_TBUF+ (size_t)16 * 16 * 1024;
constexpr size_t N_FLG   = (size_t)8 * 256 * 32;            // [group][pid][member]
constexpr size_t WS_NEED = (WS_FLOATS + N_FLG + 512 + 64) * 4;

// ---- LDS float offsets ----
constexpr int SM_WHH = 0;       // 16*3*512 = 24576
constexpr int SM_ST  = 24576;   // 2*512 staging
constexpr int SM_QM  = 25600;   // [b*2+qm][j<15][ig]  2*2*15*16 = 960
constexpr int SM_PS  = 26560;   // [b][ig][vj] 512
constexpr int SM_GC  = 27072;   // [q/m][ig][j] 512
constexpr int SM_GIL = 27584;   // [b][r][ig] 96
constexpr int SM_BHH = 27680;   // [r][ig] 48
constexpr int SM_GB  = 27728;   // 16
constexpr int SM_MB  = 27744;   // 16
constexpr int SM_DEP = 27760;   // [b][j] 32
constexpr int SM_TOT = 27792;
// F-phase reuse (whh region dead after scan)
constexpr int SM_BHJ = 8192;    // [j<15][128]
constexpr int SM_RED = 10112;   // 260
} // namespace

DEVFN float sigf(float x)  { return 1.0f / (1.0f + __expf(-x)); }
DEVFN float tanhf_(float x){ float e2 = __expf(2.0f * x); return 1.0f - 2.0f / (e2 + 1.0f); }
DEVFN void  stgf(float* p, float v) { __hip_atomic_store(p, v, __ATOMIC_RELAXED, __HIP_MEMORY_SCOPE_AGENT); }
DEVFN size_t hslotf(int b, int slot) { return OFF_HSEQ + ((size_t)b * 136 + slot) * 512; }
DEVFN int trif(int idx) { return idx * (idx + 1) / 2; }

struct KArgs {
  const float* in[21];
  float* out;
  float* wsf;
};

// ================= init kernel: repack weights, gi, gs0, zero out/flags ==========
__global__ __launch_bounds__(256) void k0_init(KArgs a) {
  const float* z    = a.in[0];  const float* enc  = a.in[2];
  const float* lin1w= a.in[3];  const float* lin1b= a.in[4];
  const float* av1w = a.in[5];
  const float* ae1w = a.in[9];
  const float* gatew= a.in[13]; const float* mapw = a.in[15];
  const float* wih  = a.in[17]; const float* bih  = a.in[18];
  const float* whh  = a.in[19];
  float* wsf = a.wsf;
  const int gtid = blockIdx.x * 256 + threadIdx.x;
  const int NTH = 256 * 256;

  for (size_t t = gtid; t < (size_t)512 * 512; t += NTH) {
    int i = t >> 9, k = t & 511;
    bool ok = (i < Hc && k < Hc);
    wsf[OFF_WGP + t] = ok ? gatew[(size_t)i * Gc + k] : 0.f;
    wsf[OFF_WMP + t] = ok ? mapw [(size_t)i * Gc + k] : 0.f;
  }
  for (size_t t = gtid; t < (size_t)512 * 1536; t += NTH) {
    int i = t / 1536, rk = t % 1536, r = rk >> 9, k = rk & 511;
    wsf[OFF_WHP + t] = (i < Hc && k < Hc) ? whh[((size_t)r * Hc + i) * Hc + k] : 0.f;
  }
  for (size_t t = gtid; t < (size_t)2048 * 512; t += NTH) {
    int r = t >> 9, k = t & 511;
    bool ok = (r < 2004 && k < Hc);
    wsf[OFF_WHV + t] = ok ? ae1w[(size_t)r * 1002 + k]      : 0.f;
    wsf[OFF_WHJ + t] = ok ? ae1w[(size_t)r * 1002 + Hc + k] : 0.f;
  }
  for (size_t t = gtid; t < (size_t)1024 * 512; t += NTH) {
    int r = t >> 9, k = t & 511;
    wsf[OFF_WAV + t] = (r < 1002 && k < Hc) ? av1w[(size_t)r * Hc + k] : 0.f;
  }
  for (size_t t = gtid; t < (size_t)512 * 16; t += NTH) {
    int i = t >> 4, j = t & 15;
    wsf[OFF_GCOL + t] = (i < Hc) ? gatew[(size_t)i * Gc + Hc + j] : 0.f;
    wsf[OFF_MCOL + t] = (i < Hc) ? mapw [(size_t)i * Gc + Hc + j] : 0.f;
  }
  for (size_t t = gtid; t < (size_t)16 * 16 * 1503; t += NTH) {
    int r = t % 1503; size_t bi = t / 1503;
    float acc = bih[r];
    const float* x = enc + bi * 10;
    const float* w = wih + (size_t)r * 10;
    #pragma unroll
    for (int c = 0; c < 10; ++c) acc = fmaf(w[c], x[c], acc);
    wsf[OFF_GI + bi * 1536 + r] = acc;
  }
  for (size_t t = gtid; t < (size_t)16 * 512; t += NTH) {
    int b = t >> 9, i = t & 511;
    float v = 0.f;
    if (i < Hc) {
      float acc = lin1b[i];
      const float* zz = z + (size_t)b * 56;
      const float* w  = lin1w + (size_t)i * 56;
      for (int k = 0; k < 56; ++k) acc = fmaf(w[k], zz[k], acc);
      v = acc;
    }
    wsf[OFF_GS0 + t] = v;
  }
  for (size_t t = gtid; t < 4096; t += NTH) a.out[t] = 0.f;   // gen_dep zero (atomics)
  unsigned* FLG = (unsigned*)a.wsf + WS_FLOATS;
  for (size_t t = gtid; t < N_FLG + 512; t += NTH) FLG[t] = 0u;
}

// ================= main persistent kernel ==========
__global__ __launch_bounds__(256, 1) void k1_main(KArgs a) {
  const int blk = blockIdx.x, tid = threadIdx.x;
  const int g = blk >> 5, m = blk & 31;        // group (2 batches), member
  const int ig = tid >> 4, l = tid & 15;       // i-subgroup, k-lane
  const int i = m * 16 + ig;                   // owned row
  float* wsf = a.wsf;
  unsigned* FLG = (unsigned*)a.wsf + WS_FLOATS;
  unsigned* F1F = FLG + N_FLG;                 // 256 words
  unsigned* GBR = F1F + 256;                   // 256 words: one-shot global barrier
  const float* dep  = a.in[1];
  const float* gateb= a.in[14]; const float* mapb = a.in[16];
  const float* bhh  = a.in[20];

  __shared__ float smem[SM_TOT];
  int pid = 0;

  // ---- persistent loads: Whh slice -> LDS; Wg/Wm slice -> VGPRs; small tables ----
  {
    float4* d = (float4*)smem;
    const float4* s = ((const float4*)(wsf + OFF_WHP)) + (size_t)m * 6144;
    for (int t = tid; t < 6144; t += 256) d[t] = s[t];
    for (int t = tid; t < 512; t += 256) {
      int q = t >> 8, r2 = t & 255, ii = r2 >> 4, j = r2 & 15;
      smem[SM_GC + t] = wsf[(q ? OFF_MCOL : OFF_GCOL) + (size_t)(m * 16 + ii) * 16 + j];
    }
    if (tid < 16) {
      int iG = m * 16 + tid;
      smem[SM_GB + tid] = (iG < Hc) ? gateb[iG] : 0.f;
      smem[SM_MB + tid] = (iG < Hc) ? mapb[iG]  : 0.f;
    }
    if (tid < 48) {
      int r = tid >> 4, ii = tid & 15, iG = m * 16 + ii;
      smem[SM_BHH + tid] = (iG < Hc) ? bhh[r * Hc + iG] : 0.f;
    }
  }
  // Wg/Wm fragments: lane l owns float4s {t*16+l}, bank-friendly pairing with LDS h reads
  float4 wgr[8], wmr[8];
  {
    const float4* pg = ((const float4*)(wsf + OFF_WGP)) + (size_t)i * 128;
    const float4* pm = ((const float4*)(wsf + OFF_WMP)) + (size_t)i * 128;
    #pragma unroll
    for (int t = 0; t < 8; ++t) { wgr[t] = pg[t * 16 + l]; wmr[t] = pm[t * 16 + l]; }
  }
  __syncthreads();

  // ---- group barrier: 32 parallel sentinel stores; 32 lanes poll ----
  auto flagbar = [&]() {
    __syncthreads();    // drains this block's vmem before flag store
    if (tid == 0)
      __hip_atomic_store(FLG + ((size_t)g * 256 + pid) * 32 + m, (unsigned)(pid + 1),
                         __ATOMIC_RELEASE, __HIP_MEMORY_SCOPE_AGENT);
    if (tid < 32) {
      unsigned* p = FLG + ((size_t)g * 256 + pid) * 32 + tid;
      while (__hip_atomic_load(p, __ATOMIC_RELAXED, __HIP_MEMORY_SCOPE_AGENT) != (unsigned)(pid + 1))
        __builtin_amdgcn_s_sleep(4);
    }
    __syncthreads();
    ++pid;
  };

  auto stage2v = [&](size_t o0, size_t o1) {   // load 2 h-vectors (b0,b1) into LDS
    float4* d = (float4*)(smem + SM_ST);
    if (tid < 128) d[tid] = ((const float4*)(wsf + o0))[tid];
    else           d[tid] = ((const float4*)(wsf + o1))[tid - 128];
  };
  auto stagegi = [&](int index) {
    if (tid >= 64 && tid < 160) {
      int t = tid - 64, b = t / 48, r = (t / 16) % 3, ii = t & 15, iG = m * 16 + ii;
      smem[SM_GIL + (b * 3 + r) * 16 + ii] =
        (iG < Hc) ? wsf[OFF_GI + ((size_t)(2 * g + b) * 16 + index) * 1536 + (size_t)r * Hc + iG] : 0.f;
    }
  };
  // Wg/Wm row-i dot with BOTH staged batches; k4 = t*16+l (bank l*4 -> 2-way, free)
  auto s1core = [&](float& aq0, float& am0, float& aq1, float& am1) {
    const float4* h0 = (const float4*)(smem + SM_ST);
    const float4* h1 = (const float4*)(smem + SM_ST + 512);
    float q0 = 0.f, m0 = 0.f, q1 = 0.f, m1 = 0.f;
    #pragma unroll
    for (int t = 0; t < 8; ++t) {
      int k4 = t * 16 + l;
      float4 a0 = h0[k4], a1 = h1[k4];
      q0 = fmaf(wgr[t].x, a0.x, q0); q0 = fmaf(wgr[t].y, a0.y, q0);
      q0 = fmaf(wgr[t].z, a0.z, q0); q0 = fmaf(wgr[t].w, a0.w, q0);
      m0 = fmaf(wmr[t].x, a0.x, m0); m0 = fmaf(wmr[t].y, a0.y, m0);
      m0 = fmaf(wmr[t].z, a0.z, m0); m0 = fmaf(wmr[t].w, a0.w, m0);
      q1 = fmaf(wgr[t].x, a1.x, q1); q1 = fmaf(wgr[t].y, a1.y, q1);
      q1 = fmaf(wgr[t].z, a1.z, q1); q1 = fmaf(wgr[t].w, a1.w, q1);
      m1 = fmaf(wmr[t].x, a1.x, m1); m1 = fmaf(wmr[t].y, a1.y, m1);
      m1 = fmaf(wmr[t].z, a1.z, m1); m1 = fmaf(wmr[t].w, a1.w, m1);
    }
    q0 += __shfl_xor(q0, 1); q0 += __shfl_xor(q0, 2); q0 += __shfl_xor(q0, 4); q0 += __shfl_xor(q0, 8);
    m0 += __shfl_xor(m0, 1); m0 += __shfl_xor(m0, 2); m0 += __shfl_xor(m0, 4); m0 += __shfl_xor(m0, 8);
    q1 += __shfl_xor(q1, 1); q1 += __shfl_xor(q1, 2); q1 += __shfl_xor(q1, 4); q1 += __shfl_xor(q1, 8);
    m1 += __shfl_xor(m1, 1); m1 += __shfl_xor(m1, 2); m1 += __shfl_xor(m1, 4); m1 += __shfl_xor(m1, 8);
    aq0 = q0; am0 = m0; aq1 = q1; am1 = m1;
  };
  // gh = Whh@lds_st (both batches, weights read once), GRU elementwise, store hv slice
  auto s2core = [&](int dstSlot) {
    const float4* W  = ((const float4*)smem) + ig * 384;
    const float4* h0 = (const float4*)(smem + SM_ST);
    const float4* h1 = (const float4*)(smem + SM_ST + 512);
    float gr0 = 0.f, gz0 = 0.f, gn0 = 0.f, gr1 = 0.f, gz1 = 0.f, gn1 = 0.f;
    #pragma unroll
    for (int t = 0; t < 8; ++t) {
      int k4 = t * 16 + l;
      float4 hv0 = h0[k4], hv1 = h1[k4];
      float4 a0 = W[k4], a1 = W[128 + k4], a2 = W[256 + k4];
      gr0 = fmaf(a0.x, hv0.x, gr0); gr0 = fmaf(a0.y, hv0.y, gr0); gr0 = fmaf(a0.z, hv0.z, gr0); gr0 = fmaf(a0.w, hv0.w, gr0);
      gz0 = fmaf(a1.x, hv0.x, gz0); gz0 = fmaf(a1.y, hv0.y, gz0); gz0 = fmaf(a1.z, hv0.z, gz0); gz0 = fmaf(a1.w, hv0.w, gz0);
      gn0 = fmaf(a2.x, hv0.x, gn0); gn0 = fmaf(a2.y, hv0.y, gn0); gn0 = fmaf(a2.z, hv0.z, gn0); gn0 = fmaf(a2.w, hv0.w, gn0);
      gr1 = fmaf(a0.x, hv1.x, gr1); gr1 = fmaf(a0.y, hv1.y, gr1); gr1 = fmaf(a0.z, hv1.z, gr1); gr1 = fmaf(a0.w, hv1.w, gr1);
      gz1 = fmaf(a1.x, hv1.x, gz1); gz1 = fmaf(a1.y, hv1.y, gz1); gz1 = fmaf(a1.z, hv1.z, gz1); gz1 = fmaf(a1.w, hv1.w, gz1);
      gn1 = fmaf(a2.x, hv1.x, gn1); gn1 = fmaf(a2.y, hv1.y, gn1); gn1 = fmaf(a2.z, hv1.z, gn1); gn1 = fmaf(a2.w, hv1.w, gn1);
    }
    gr0 += __shfl_xor(gr0, 1); gr0 += __shfl_xor(gr0, 2); gr0 += __shfl_xor(gr0, 4); gr0 += __shfl_xor(gr0, 8);
    gz0 += __shfl_xor(gz0, 1); gz0 += __shfl_xor(gz0, 2); gz0 += __shfl_xor(gz0, 4); gz0 += __shfl_xor(gz0, 8);
    gn0 += __shfl_xor(gn0, 1); gn0 += __shfl_xor(gn0, 2); gn0 += __shfl_xor(gn0, 4); gn0 += __shfl_xor(gn0, 8);
    gr1 += __shfl_xor(gr1, 1); gr1 += __shfl_xor(gr1, 2); gr1 += __shfl_xor(gr1, 4); gr1 += __shfl_xor(gr1, 8);
    gz1 += __shfl_xor(gz1, 1); gz1 += __shfl_xor(gz1, 2); gz1 += __shfl_xor(gz1, 4); gz1 += __shfl_xor(gz1, 8);
    gn1 += __shfl_xor(gn1, 1); gn1 += __shfl_xor(gn1, 2); gn1 += __shfl_xor(gn1, 4); gn1 += __shfl_xor(gn1, 8);
    if (l < 2) {
      int b = l;
      float gr = l ? gr1 : gr0, gz = l ? gz1 : gz0, gn = l ? gn1 : gn0;
      float h  = smem[SM_ST + b * 512 + i];   // GRU hidden input (the staged h_in)
      float rr = sigf(smem[SM_GIL + (b * 3 + 0) * 16 + ig] + gr + smem[SM_BHH + 0 + ig]);
      float uu = sigf(smem[SM_GIL + (b * 3 + 1) * 16 + ig] + gz + smem[SM_BHH + 16 + ig]);
      float nn = tanhf_(smem[SM_GIL + (b * 3 + 2) * 16 + ig] + rr * (gn + smem[SM_BHH + 32 + ig]));
      float v = (1.f - uu) * nn + uu * h;
      if (i >= Hc) v = 0.f;
      stgf(wsf + hslotf(2 * g + b, dstSlot) + i, v);
    }
  };

  // ================= phase 0: hv(idx0) = GRU(x0, gs0) =================
  stage2v(OFF_GS0 + (size_t)(2 * g) * 512, OFF_GS0 + (size_t)(2 * g + 1) * 512);
  stagegi(0);
  __syncthreads();
  s2core(0);
  flagbar();

  // ================= scan =================
  for (int index = 1; index < 16; ++index) {
    // ---- phase A: QM-finalize(index-1), PS build, hv0, h_in(s=0) ----
    stage2v(hslotf(2 * g,     trif(index - 1) + index - 1),
            hslotf(2 * g + 1, trif(index - 1) + index - 1));
    if (tid < 32) {
      int b = tid >> 4, j = tid & 15;
      smem[SM_DEP + b * 16 + j] = dep[((size_t)(2 * g + b) * 16 + index) * 16 + j];
    }
    stagegi(index);
    __syncthreads();
    {
      float aq0, am0, aq1, am1;
      s1core(aq0, am0, aq1, am1);
      if (l < 2) {
        float aq = l ? aq1 : aq0, am = l ? am1 : am0;
        smem[SM_QM + ((l * 2 + 0) * 15 + (index - 1)) * 16 + ig] = aq + smem[SM_GC + ig * 16 + (index - 1)];
        smem[SM_QM + ((l * 2 + 1) * 15 + (index - 1)) * 16 + ig] = am + smem[SM_GC + 256 + ig * 16 + (index - 1)];
      }
    }
    __syncthreads();
    if (l < 2) {               // PS backward cumsum, b = l
      float acc = 0.f, gb = smem[SM_GB + ig], mb = smem[SM_MB + ig];
      for (int j = 15; j >= 0; --j) {
        if (j != index) {
          float aa = smem[SM_DEP + l * 16 + j];
          float q, mm;
          if (j < index) { q = smem[SM_QM + ((l * 2 + 0) * 15 + j) * 16 + ig];
                           mm = smem[SM_QM + ((l * 2 + 1) * 15 + j) * 16 + ig]; }
          else           { q = smem[SM_GC + ig * 16 + j];
                           mm = smem[SM_GC + 256 + ig * 16 + j]; }
          float sg = sigf(fmaf(aa, q, gb));
          acc = fmaf(aa * sg, fmaf(aa, mm, mb), acc);
        }
        smem[SM_PS + (l * 16 + ig) * 16 + j] = acc;
      }
    } else if (l < 4) {        // hv0 = gru(x,0), b = l-2
      int b = l - 2;
      float rr = sigf(smem[SM_GIL + (b * 3 + 0) * 16 + ig] + smem[SM_BHH + 0 + ig]);
      float uu = sigf(smem[SM_GIL + (b * 3 + 1) * 16 + ig] + smem[SM_BHH + 16 + ig]);
      float nn = tanhf_(smem[SM_GIL + (b * 3 + 2) * 16 + ig] + rr * smem[SM_BHH + 32 + ig]);
      float v = (1.f - uu) * nn;
      if (i >= Hc) v = 0.f;
      stgf(wsf + hslotf(2 * g + b, trif(index) + 0) + i, v);
    }
    __syncthreads();
    if (l < 2) {               // h_in(s=0): row-index term has ZERO hidden (nhs[:,index]=0)
      int b = l;
      float gb = smem[SM_GB + ig], mb = smem[SM_MB + ig];
      float aI = smem[SM_DEP + b * 16 + index];
      float Qi = smem[SM_GC + ig * 16 + index], Mi = smem[SM_GC + 256 + ig * 16 + index];
      float f = aI * sigf(fmaf(aI, Qi, gb)) * fmaf(aI, Mi, mb);
      float v = smem[SM_PS + (b * 16 + ig) * 16 + (index - 1)] + f;
      if (i >= Hc) v = 0.f;
      stgf(wsf + OFF_HINS + ((size_t)(index * (index - 1) / 2 + 0) * 16 + (2 * g + b)) * 512 + i, v);
    }
    flagbar();

    for (int s = 0; s < index; ++s) {
      // ---- S2(s): hv_{s+1} = GRU(x, h_in_s) ----
      stage2v(OFF_HINS + ((size_t)(index * (index - 1) / 2 + s) * 16 + (2 * g + 0)) * 512,
              OFF_HINS + ((size_t)(index * (index - 1) / 2 + s) * 16 + (2 * g + 1)) * 512);
      __syncthreads();
      s2core(trif(index) + s + 1);
      flagbar();
      if (s + 1 < index) {
        // ---- S1(s+1): h_in = PS[vj] + f(Wg/Wm @ hv_{s+1}) ----
        int ss = s + 1, vj = index - 1 - ss;
        stage2v(hslotf(2 * g, trif(index) + ss), hslotf(2 * g + 1, trif(index) + ss));
        __syncthreads();
        {
          float aq0, am0, aq1, am1;
          s1core(aq0, am0, aq1, am1);
          if (l < 2) {
            int b = l;
            float aq = l ? aq1 : aq0, am = l ? am1 : am0;
            float gb = smem[SM_GB + ig], mb = smem[SM_MB + ig];
            float aI = smem[SM_DEP + b * 16 + index];
            float Qi = aq + smem[SM_GC + ig * 16 + index];
            float Mi = am + smem[SM_GC + 256 + ig * 16 + index];
            float f = aI * sigf(fmaf(aI, Qi, gb)) * fmaf(aI, Mi, mb);
            float v = smem[SM_PS + (b * 16 + ig) * 16 + vj] + f;
            if (i >= Hc) v = 0.f;
            stgf(wsf + OFF_HINS + ((size_t)(index * (index - 1) / 2 + ss) * 16 + (2 * g + b)) * 512 + i, v);
          }
        }
        flagbar();
      }
    }
  }

  // ---- one-shot GLOBAL barrier: F reads other groups' hv slots ----
  {
    __syncthreads();
    if (tid == 0)
      __hip_atomic_store(GBR + blk, 1u, __ATOMIC_RELEASE, __HIP_MEMORY_SCOPE_AGENT);
    unsigned* p = GBR + tid;   // 256 threads, 1 flag each
    while (__hip_atomic_load(p, __ATOMIC_RELAXED, __HIP_MEMORY_SCOPE_AGENT) != 1u)
      __builtin_amdgcn_s_sleep(4);
    __syncthreads();
  }

  // ================= F phases: deferred edges + node encodings =================
  {
    const int b = blk >> 4, rs = blk & 15;
    const int il = tid >> 3, l8 = tid & 7;
    float4* lds4 = (float4*)smem;
    // ---- F1a: Bhj = W_hj @ nhs_j (j<15) -> LDS ----
    for (int t = tid; t < 2048; t += 256) {
      int j = t >> 7, k4 = t & 127;
      float4 v = {0.f, 0.f, 0.f, 0.f};
      if (j < 15) v = ((const float4*)(wsf + hslotf(b, trif(j) + j)))[k4];
      lds4[t] = v;
    }
    __syncthreads();
    for (int half = 0; half < 2; ++half) {
      int jbase = half * 8;
      float acc[4][8];
      #pragma unroll
      for (int q = 0; q < 4; ++q)
        #pragma unroll
        for (int j = 0; j < 8; ++j) acc[q][j] = 0.f;
      int rbase = rs * 126 + il * 4;
      #pragma unroll
      for (int s2 = 0; s2 < 16; ++s2) {
        int k4 = s2 * 8 + l8;
        float4 h4v[8];
        #pragma unroll
        for (int j = 0; j < 8; ++j) h4v[j] = lds4[(jbase + j) * 128 + k4];
        #pragma unroll
        for (int q = 0; q < 4; ++q) {
          float4 wv = ((const float4*)(wsf + OFF_WHJ))[(size_t)(rbase + q) * 128 + k4];
          #pragma unroll
          for (int j = 0; j < 8; ++j) {
            acc[q][j] = fmaf(wv.x, h4v[j].x, acc[q][j]); acc[q][j] = fmaf(wv.y, h4v[j].y, acc[q][j]);
            acc[q][j] = fmaf(wv.z, h4v[j].z, acc[q][j]); acc[q][j] = fmaf(wv.w, h4v[j].w, acc[q][j]);
          }
        }
      }
      #pragma unroll
      for (int q = 0; q < 4; ++q) {
        bool rowok = (il * 4 + q < 126) && (rbase + q < 2004);
        #pragma unroll
        for (int j = 0; j < 8; ++j) {
          float v = acc[q][j];
          v += __shfl_xor(v, 1); v += __shfl_xor(v, 2); v += __shfl_xor(v, 4);
          if (l8 == 0 && rowok && (jbase + j) < 15)
            smem[SM_BHJ + (jbase + j) * 128 + il * 4 + q] = v;
        }
      }
    }
    __syncthreads();
    // ---- F1b: TBUF = relu(av1 @ graph_state list) ----
    for (int t = tid; t < 2048; t += 256) {
      int idx = t >> 7, k4 = t & 127;
      const float4* src = (idx == 0)
        ? ((const float4*)(wsf + OFF_GS0 + (size_t)b * 512))
        : ((const float4*)(wsf + hslotf(b, trif(idx - 1) + idx - 1)));
      lds4[t] = src[k4];
    }
    __syncthreads();
    const float* av1b = a.in[6];
    for (int half = 0; half < 2; ++half) {
      int jbase = half * 8;
      float acc[2][8];
      #pragma unroll
      for (int q = 0; q < 2; ++q)
        #pragma unroll
        for (int j = 0; j < 8; ++j) acc[q][j] = 0.f;
      int rbase = rs * 63 + il * 2;
      #pragma unroll
      for (int s2 = 0; s2 < 16; ++s2) {
        int k4 = s2 * 8 + l8;
        float4 h4v[8];
        #pragma unroll
        for (int j = 0; j < 8; ++j) h4v[j] = lds4[(jbase + j) * 128 + k4];
        #pragma unroll
        for (int q = 0; q < 2; ++q) {
          float4 wv = ((const float4*)(wsf + OFF_WAV))[(size_t)(rbase + q) * 128 + k4];
          #pragma unroll
          for (int j = 0; j < 8; ++j) {
            acc[q][j] = fmaf(wv.x, h4v[j].x, acc[q][j]); acc[q][j] = fmaf(wv.y, h4v[j].y, acc[q][j]);
            acc[q][j] = fmaf(wv.z, h4v[j].z, acc[q][j]); acc[q][j] = fmaf(wv.w, h4v[j].w, acc[q][j]);
          }
        }
      }
      #pragma unroll
      for (int q = 0; q < 2; ++q) {
        int r = rbase + q;
        bool rowok = (il * 2 + q < 63) && (r < 1002);
        float b1 = rowok ? av1b[r] : 0.f;
        #pragma unroll
        for (int j = 0; j < 8; ++j) {
          float v = acc[q][j];
          v += __shfl_xor(v, 1); v += __shfl_xor(v, 2); v += __shfl_xor(v, 4);
          if (l8 == 0 && rowok)
            stgf(wsf + OFF_TBUF + ((size_t)b * 16 + jbase + j) * 1024 + r, fmaxf(v + b1, 0.f));
        }
      }
    }
    __syncthreads();
    if (tid == 0)
      __hip_atomic_store(F1F + b * 16 + rs, 1u, __ATOMIC_RELEASE, __HIP_MEMORY_SCOPE_AGENT);

    // ---- F2: all 120 edges per batch ----
    const float* ae1b = a.in[10]; const float* ae2w = a.in[11]; const float* ae2b = a.in[12];
    for (int chunk = 0; chunk < 15; ++chunk) {
      int idxs[8], vjs[8]; bool tval[8];
      #pragma unroll
      for (int j = 0; j < 8; ++j) {
        int e = chunk * 8 + j;
        if (e < 120) {
          int ix = 1, rem = e;
          while (rem >= ix) { rem -= ix; ++ix; }
          idxs[j] = ix; vjs[j] = rem; tval[j] = true;
        } else { idxs[j] = 1; vjs[j] = 0; tval[j] = false; }
      }
      __syncthreads();
      for (int t = tid; t < 1024; t += 256) {
        int sl = t >> 7, k4 = t & 127;
        int sE = idxs[sl] - 1 - vjs[sl];
        lds4[t] = ((const float4*)(wsf + hslotf(b, trif(idxs[sl]) + sE)))[k4];
      }
      __syncthreads();
      float part[8];
      #pragma unroll
      for (int j = 0; j < 8; ++j) part[j] = 0.f;
      int rbase = rs * 126 + il * 4;
      float acc[4][8];
      #pragma unroll
      for (int q = 0; q < 4; ++q)
        #pragma unroll
        for (int j = 0; j < 8; ++j) acc[q][j] = 0.f;
      #pragma unroll
      for (int s2 = 0; s2 < 16; ++s2) {
        int k4 = s2 * 8 + l8;
        float4 h4v[8];
        #pragma unroll
        for (int j = 0; j < 8; ++j) h4v[j] = lds4[j * 128 + k4];
        #pragma unroll
        for (int q = 0; q < 4; ++q) {
          float4 wv = ((const float4*)(wsf + OFF_WHV))[(size_t)(rbase + q) * 128 + k4];
          #pragma unroll
          for (int j = 0; j < 8; ++j) {
            acc[q][j] = fmaf(wv.x, h4v[j].x, acc[q][j]); acc[q][j] = fmaf(wv.y, h4v[j].y, acc[q][j]);
            acc[q][j] = fmaf(wv.z, h4v[j].z, acc[q][j]); acc[q][j] = fmaf(wv.w, h4v[j].w, acc[q][j]);
          }
        }
      }
      #pragma unroll
      for (int q = 0; q < 4; ++q) {
        int r = rbase + q;
        bool rowok = (il * 4 + q < 126) && (r < 2004);
        float aer = rowok ? ae2w[r] : 0.f;
        float b1r = rowok ? ae1b[r] : 0.f;
        #pragma unroll
        for (int j = 0; j < 8; ++j) {
          float v = acc[q][j];
          v += __shfl_xor(v, 1); v += __shfl_xor(v, 2); v += __shfl_xor(v, 4);
          if (l8 == 0 && rowok && tval[j]) {
            float bh = smem[SM_BHJ + vjs[j] * 128 + il * 4 + q];
            part[j] = fmaf(aer, fmaxf(v + bh + b1r, 0.f), part[j]);
          }
        }
      }
      if (l8 == 0) {
        #pragma unroll
        for (int j = 0; j < 8; ++j) smem[SM_RED + il * 8 + j] = part[j];
      }
      __syncthreads();
      if (tid < 8) {
        float v = 0.f;
        for (int q = 0; q < 32; ++q) v += smem[SM_RED + q * 8 + tid];
        if (rs == 0) v += ae2b[0];
        if (tval[tid])
          atomicAdd(a.out + ((size_t)b * 16 + idxs[tid]) * 16 + vjs[tid], v);
      }
      __syncthreads();
    }
    // ---- F3: gen_node_encoding[(b, rs)] ----
    if (tid < 16) {
      unsigned* p = F1F + b * 16 + tid;
      while (__hip_atomic_load(p, __ATOMIC_RELAXED, __HIP_MEMORY_SCOPE_AGENT) != 1u)
        __builtin_amdgcn_s_sleep(4);
    }
    __syncthreads();
    {
      const float* av2w = a.in[7]; const float* av2b = a.in[8];
      const float* tb = wsf + OFF_TBUF + ((size_t)b * 16 + rs) * 1024;
      float accn[10];
      #pragma unroll
      for (int c = 0; c < 10; ++c) accn[c] = 0.f;
      for (int r = tid; r < 1002; r += 256) {
        float tv = tb[r];
        #pragma unroll
        for (int c = 0; c < 10; ++c) accn[c] = fmaf(av2w[(size_t)c * 1002 + r], tv, accn[c]);
      }
      #pragma unroll
      for (int c = 0; c < 10; ++c) {
        float v = accn[c];
        for (int m2 = 1; m2 < 64; m2 <<= 1) v += __shfl_xor(v, m2);
        if ((tid & 63) == 0) smem[SM_RED + (tid >> 6) * 10 + c] = v;
      }
      __syncthreads();
      if (tid == 0) {
        for (int c = 0; c < 10; ++c) {
          float v = av2b[c] + smem[SM_RED + c] + smem[SM_RED + 10 + c] + smem[SM_RED + 20 + c] + smem[SM_RED + 30 + c];
          stgf(a.out + 4096 + ((size_t)b * 16 + rs) * 10 + c, v);
        }
      }
    }
  }
}

extern "C" void kernel_launch(void* const* d_in, const int* in_sizes, int n_in,
                              void* d_out, int out_size, void* d_ws, size_t ws_size,
                              hipStream_t stream) {
  (void)in_sizes; (void)n_in; (void)out_size;
  if (ws_size < WS_NEED) return;   // fail loudly via validation
  KArgs a;
  for (int k = 0; k < 21; ++k) a.in[k] = (const float*)d_in[k];
  a.out = (float*)d_out;
  a.wsf = (float*)d_ws;
  k0_init<<<256, 256, 0, stream>>>(a);
  k1_main<<<256, 256, 0, stream>>>(a);
}

// Round 5
// 3184.338 us; speedup vs baseline: 1.5668x; 1.0919x over previous
//
#include <hip/hip_runtime.h>

#define DEVFN static __device__ __forceinline__

namespace {
constexpr int Hc = 501, Gc = 517;
// ---- workspace float offsets ----
constexpr size_t OFF_WGP = 0;                               // [512][512] gate_w[:, :H] padded
constexpr size_t OFF_WMP = OFF_WGP + (size_t)512 * 512;     // map_w[:, :H]
constexpr size_t OFF_WHP = OFF_WMP + (size_t)512 * 512;     // w_hh packed [i][3][512]
constexpr size_t OFF_WHV = OFF_WHP + (size_t)512 * 1536;    // ae1_w[:, :H]  [2048][512]
constexpr size_t OFF_WHJ = OFF_WHV + (size_t)2048 * 512;    // ae1_w[:, H:]  [2048][512]
constexpr size_t OFF_WAV = OFF_WHJ + (size_t)2048 * 512;    // av1_w [1024][512]
constexpr size_t OFF_GCOL= OFF_WAV + (size_t)1024 * 512;    // gate_w[:, H+j] [512][16]
constexpr size_t OFF_MCOL= OFF_GCOL + (size_t)512 * 16;
constexpr size_t OFF_GI  = OFF_MCOL + (size_t)512 * 16;     // [16][16][1536]
constexpr size_t OFF_GS0 = OFF_GI  + (size_t)16 * 16 * 1536;// [16][512]
constexpr size_t OFF_HSEQ= OFF_GS0 + (size_t)16 * 512;      // [16 b][136 slot][512]
constexpr size_t OFF_HINS= OFF_HSEQ+ (size_t)16 * 136 * 512;// [120 slot][16 b][512]
constexpr size_t OFF_TBUF= OFF_HINS+ (size_t)120 * 16 * 512;// [16 b][16 idx][1024]
constexpr size_t WS_FLOATS=OFF_TBUF+ (size_t)16 * 16 * 1024;
constexpr size_t N_FLG   = (size_t)8 * 256 * 32;            // [group][pid][member]
constexpr size_t WS_NEED = (WS_FLOATS + N_FLG + 512 + 64) * 4;

// ---- k1 LDS float offsets ----
constexpr int SM_WHH = 0;       // 16*3*512 = 24576
constexpr int SM_ST  = 24576;   // 2*512 staging
constexpr int SM_QM  = 25600;   // [b*2+qm][j<15][ig]  2*2*15*16 = 960
constexpr int SM_PS  = 26560;   // [b][ig][vj] 512
constexpr int SM_GC  = 27072;   // [q/m][ig][j] 512
constexpr int SM_GIL = 27584;   // [b][r][ig] 96
constexpr int SM_BHH = 27680;   // [r][ig] 48
constexpr int SM_GB  = 27728;   // 16
constexpr int SM_MB  = 27744;   // 16
constexpr int SM_DEP = 27760;   // [b][j] 32
constexpr int SM_TOT = 27792;
// ---- k2 LDS float offsets ----
constexpr int F_BHJ = 8192;     // [j<15][128]  (after 2048-float4 staging)
constexpr int F_RED = 10112;    // 260
constexpr int F_TOT = 10376;
} // namespace

DEVFN float sigf(float x)  { return 1.0f / (1.0f + __expf(-x)); }
DEVFN float tanhf_(float x){ float e2 = __expf(2.0f * x); return 1.0f - 2.0f / (e2 + 1.0f); }
DEVFN void  stgf(float* p, float v) { __hip_atomic_store(p, v, __ATOMIC_RELAXED, __HIP_MEMORY_SCOPE_AGENT); }
DEVFN size_t hslotf(int b, int slot) { return OFF_HSEQ + ((size_t)b * 136 + slot) * 512; }
DEVFN int trif(int idx) { return idx * (idx + 1) / 2; }

struct KArgs {
  const float* in[21];
  float* out;
  float* wsf;
};

// ================= init kernel: repack weights, gi, gs0, zero out/flags ==========
__global__ __launch_bounds__(256) void k0_init(KArgs a) {
  const float* z    = a.in[0];  const float* enc  = a.in[2];
  const float* lin1w= a.in[3];  const float* lin1b= a.in[4];
  const float* av1w = a.in[5];
  const float* ae1w = a.in[9];
  const float* gatew= a.in[13]; const float* mapw = a.in[15];
  const float* wih  = a.in[17]; const float* bih  = a.in[18];
  const float* whh  = a.in[19];
  float* wsf = a.wsf;
  const int gtid = blockIdx.x * 256 + threadIdx.x;
  const int NTH = 256 * 256;

  for (size_t t = gtid; t < (size_t)512 * 512; t += NTH) {
    int i = t >> 9, k = t & 511;
    bool ok = (i < Hc && k < Hc);
    wsf[OFF_WGP + t] = ok ? gatew[(size_t)i * Gc + k] : 0.f;
    wsf[OFF_WMP + t] = ok ? mapw [(size_t)i * Gc + k] : 0.f;
  }
  for (size_t t = gtid; t < (size_t)512 * 1536; t += NTH) {
    int i = t / 1536, rk = t % 1536, r = rk >> 9, k = rk & 511;
    wsf[OFF_WHP + t] = (i < Hc && k < Hc) ? whh[((size_t)r * Hc + i) * Hc + k] : 0.f;
  }
  for (size_t t = gtid; t < (size_t)2048 * 512; t += NTH) {
    int r = t >> 9, k = t & 511;
    bool ok = (r < 2004 && k < Hc);
    wsf[OFF_WHV + t] = ok ? ae1w[(size_t)r * 1002 + k]      : 0.f;
    wsf[OFF_WHJ + t] = ok ? ae1w[(size_t)r * 1002 + Hc + k] : 0.f;
  }
  for (size_t t = gtid; t < (size_t)1024 * 512; t += NTH) {
    int r = t >> 9, k = t & 511;
    wsf[OFF_WAV + t] = (r < 1002 && k < Hc) ? av1w[(size_t)r * Hc + k] : 0.f;
  }
  for (size_t t = gtid; t < (size_t)512 * 16; t += NTH) {
    int i = t >> 4, j = t & 15;
    wsf[OFF_GCOL + t] = (i < Hc) ? gatew[(size_t)i * Gc + Hc + j] : 0.f;
    wsf[OFF_MCOL + t] = (i < Hc) ? mapw [(size_t)i * Gc + Hc + j] : 0.f;
  }
  for (size_t t = gtid; t < (size_t)16 * 16 * 1503; t += NTH) {
    int r = t % 1503; size_t bi = t / 1503;
    float acc = bih[r];
    const float* x = enc + bi * 10;
    const float* w = wih + (size_t)r * 10;
    #pragma unroll
    for (int c = 0; c < 10; ++c) acc = fmaf(w[c], x[c], acc);
    wsf[OFF_GI + bi * 1536 + r] = acc;
  }
  for (size_t t = gtid; t < (size_t)16 * 512; t += NTH) {
    int b = t >> 9, i = t & 511;
    float v = 0.f;
    if (i < Hc) {
      float acc = lin1b[i];
      const float* zz = z + (size_t)b * 56;
      const float* w  = lin1w + (size_t)i * 56;
      for (int k = 0; k < 56; ++k) acc = fmaf(w[k], zz[k], acc);
      v = acc;
    }
    wsf[OFF_GS0 + t] = v;
  }
  for (size_t t = gtid; t < 4096; t += NTH) a.out[t] = 0.f;   // gen_dep zero (atomics)
  unsigned* FLG = (unsigned*)a.wsf + WS_FLOATS;
  for (size_t t = gtid; t < N_FLG + 512; t += NTH) FLG[t] = 0u;
}

// ================= k1: persistent scan kernel (NO F-phase code -> low VGPR) ==========
__global__ __launch_bounds__(256, 1) void k1_scan(KArgs a) {
  const int blk = blockIdx.x, tid = threadIdx.x;
  const int g = blk >> 5, m = blk & 31;        // group (2 batches), member
  const int ig = tid >> 4, l = tid & 15;       // i-subgroup, k-lane
  const int i = m * 16 + ig;                   // owned row
  float* wsf = a.wsf;
  unsigned* FLG = (unsigned*)a.wsf + WS_FLOATS;
  const float* dep  = a.in[1];
  const float* gateb= a.in[14]; const float* mapb = a.in[16];
  const float* bhh  = a.in[20];

  __shared__ float smem[SM_TOT];
  int pid = 0;

  // ---- persistent loads: Whh slice -> LDS; Wg/Wm slice -> VGPRs; small tables ----
  {
    float4* d = (float4*)smem;
    const float4* s = ((const float4*)(wsf + OFF_WHP)) + (size_t)m * 6144;
    for (int t = tid; t < 6144; t += 256) d[t] = s[t];
    for (int t = tid; t < 512; t += 256) {
      int q = t >> 8, r2 = t & 255, ii = r2 >> 4, j = r2 & 15;
      smem[SM_GC + t] = wsf[(q ? OFF_MCOL : OFF_GCOL) + (size_t)(m * 16 + ii) * 16 + j];
    }
    if (tid < 16) {
      int iG = m * 16 + tid;
      smem[SM_GB + tid] = (iG < Hc) ? gateb[iG] : 0.f;
      smem[SM_MB + tid] = (iG < Hc) ? mapb[iG]  : 0.f;
    }
    if (tid < 48) {
      int r = tid >> 4, ii = tid & 15, iG = m * 16 + ii;
      smem[SM_BHH + tid] = (iG < Hc) ? bhh[r * Hc + iG] : 0.f;
    }
  }
  // Wg/Wm fragments: lane l owns float4s {t*16+l}
  float4 wgr[8], wmr[8];
  {
    const float4* pg = ((const float4*)(wsf + OFF_WGP)) + (size_t)i * 128;
    const float4* pm = ((const float4*)(wsf + OFF_WMP)) + (size_t)i * 128;
    #pragma unroll
    for (int t = 0; t < 8; ++t) { wgr[t] = pg[t * 16 + l]; wmr[t] = pm[t * 16 + l]; }
  }
  __syncthreads();

  // ---- group barrier: 32 parallel sentinel stores; 32 lanes poll ----
  // RELAXED is sufficient: __syncthreads drains each wave's vmem (data stores
  // complete at coherence point) before any flag store issues.
  auto flagbar = [&]() {
    __syncthreads();
    if (tid == 0)
      __hip_atomic_store(FLG + ((size_t)g * 256 + pid) * 32 + m, (unsigned)(pid + 1),
                         __ATOMIC_RELAXED, __HIP_MEMORY_SCOPE_AGENT);
    if (tid < 32) {
      unsigned* p = FLG + ((size_t)g * 256 + pid) * 32 + tid;
      while (__hip_atomic_load(p, __ATOMIC_RELAXED, __HIP_MEMORY_SCOPE_AGENT) != (unsigned)(pid + 1))
        __builtin_amdgcn_s_sleep(2);
    }
    __syncthreads();
    ++pid;
  };

  auto stage2v = [&](size_t o0, size_t o1) {   // load 2 h-vectors (b0,b1) into LDS
    float4* d = (float4*)(smem + SM_ST);
    if (tid < 128) d[tid] = ((const float4*)(wsf + o0))[tid];
    else           d[tid] = ((const float4*)(wsf + o1))[tid - 128];
  };
  auto stagegi = [&](int index) {
    if (tid >= 64 && tid < 160) {
      int t = tid - 64, b = t / 48, r = (t / 16) % 3, ii = t & 15, iG = m * 16 + ii;
      smem[SM_GIL + (b * 3 + r) * 16 + ii] =
        (iG < Hc) ? wsf[OFF_GI + ((size_t)(2 * g + b) * 16 + index) * 1536 + (size_t)r * Hc + iG] : 0.f;
    }
  };
  // Wg/Wm row-i dot with BOTH staged batches; k4 = t*16+l (2-way bank alias, free)
  auto s1core = [&](float& aq0, float& am0, float& aq1, float& am1) {
    const float4* h0 = (const float4*)(smem + SM_ST);
    const float4* h1 = (const float4*)(smem + SM_ST + 512);
    float q0 = 0.f, m0 = 0.f, q1 = 0.f, m1 = 0.f;
    #pragma unroll
    for (int t = 0; t < 8; ++t) {
      int k4 = t * 16 + l;
      float4 a0 = h0[k4], a1 = h1[k4];
      q0 = fmaf(wgr[t].x, a0.x, q0); q0 = fmaf(wgr[t].y, a0.y, q0);
      q0 = fmaf(wgr[t].z, a0.z, q0); q0 = fmaf(wgr[t].w, a0.w, q0);
      m0 = fmaf(wmr[t].x, a0.x, m0); m0 = fmaf(wmr[t].y, a0.y, m0);
      m0 = fmaf(wmr[t].z, a0.z, m0); m0 = fmaf(wmr[t].w, a0.w, m0);
      q1 = fmaf(wgr[t].x, a1.x, q1); q1 = fmaf(wgr[t].y, a1.y, q1);
      q1 = fmaf(wgr[t].z, a1.z, q1); q1 = fmaf(wgr[t].w, a1.w, q1);
      m1 = fmaf(wmr[t].x, a1.x, m1); m1 = fmaf(wmr[t].y, a1.y, m1);
      m1 = fmaf(wmr[t].z, a1.z, m1); m1 = fmaf(wmr[t].w, a1.w, m1);
    }
    q0 += __shfl_xor(q0, 1); q0 += __shfl_xor(q0, 2); q0 += __shfl_xor(q0, 4); q0 += __shfl_xor(q0, 8);
    m0 += __shfl_xor(m0, 1); m0 += __shfl_xor(m0, 2); m0 += __shfl_xor(m0, 4); m0 += __shfl_xor(m0, 8);
    q1 += __shfl_xor(q1, 1); q1 += __shfl_xor(q1, 2); q1 += __shfl_xor(q1, 4); q1 += __shfl_xor(q1, 8);
    m1 += __shfl_xor(m1, 1); m1 += __shfl_xor(m1, 2); m1 += __shfl_xor(m1, 4); m1 += __shfl_xor(m1, 8);
    aq0 = q0; am0 = m0; aq1 = q1; am1 = m1;
  };
  // gh = Whh@lds_st (both batches, weights read once), GRU elementwise, store hv slice
  auto s2core = [&](int dstSlot) {
    const float4* W  = ((const float4*)smem) + ig * 384;
    const float4* h0 = (const float4*)(smem + SM_ST);
    const float4* h1 = (const float4*)(smem + SM_ST + 512);
    float gr0 = 0.f, gz0 = 0.f, gn0 = 0.f, gr1 = 0.f, gz1 = 0.f, gn1 = 0.f;
    #pragma unroll
    for (int t = 0; t < 8; ++t) {
      int k4 = t * 16 + l;
      float4 hv0 = h0[k4], hv1 = h1[k4];
      float4 a0 = W[k4], a1 = W[128 + k4], a2 = W[256 + k4];
      gr0 = fmaf(a0.x, hv0.x, gr0); gr0 = fmaf(a0.y, hv0.y, gr0); gr0 = fmaf(a0.z, hv0.z, gr0); gr0 = fmaf(a0.w, hv0.w, gr0);
      gz0 = fmaf(a1.x, hv0.x, gz0); gz0 = fmaf(a1.y, hv0.y, gz0); gz0 = fmaf(a1.z, hv0.z, gz0); gz0 = fmaf(a1.w, hv0.w, gz0);
      gn0 = fmaf(a2.x, hv0.x, gn0); gn0 = fmaf(a2.y, hv0.y, gn0); gn0 = fmaf(a2.z, hv0.z, gn0); gn0 = fmaf(a2.w, hv0.w, gn0);
      gr1 = fmaf(a0.x, hv1.x, gr1); gr1 = fmaf(a0.y, hv1.y, gr1); gr1 = fmaf(a0.z, hv1.z, gr1); gr1 = fmaf(a0.w, hv1.w, gr1);
      gz1 = fmaf(a1.x, hv1.x, gz1); gz1 = fmaf(a1.y, hv1.y, gz1); gz1 = fmaf(a1.z, hv1.z, gz1); gz1 = fmaf(a1.w, hv1.w, gz1);
      gn1 = fmaf(a2.x, hv1.x, gn1); gn1 = fmaf(a2.y, hv1.y, gn1); gn1 = fmaf(a2.z, hv1.z, gn1); gn1 = fmaf(a2.w, hv1.w, gn1);
    }
    gr0 += __shfl_xor(gr0, 1); gr0 += __shfl_xor(gr0, 2); gr0 += __shfl_xor(gr0, 4); gr0 += __shfl_xor(gr0, 8);
    gz0 += __shfl_xor(gz0, 1); gz0 += __shfl_xor(gz0, 2); gz0 += __shfl_xor(gz0, 4); gz0 += __shfl_xor(gz0, 8);
    gn0 += __shfl_xor(gn0, 1); gn0 += __shfl_xor(gn0, 2); gn0 += __shfl_xor(gn0, 4); gn0 += __shfl_xor(gn0, 8);
    gr1 += __shfl_xor(gr1, 1); gr1 += __shfl_xor(gr1, 2); gr1 += __shfl_xor(gr1, 4); gr1 += __shfl_xor(gr1, 8);
    gz1 += __shfl_xor(gz1, 1); gz1 += __shfl_xor(gz1, 2); gz1 += __shfl_xor(gz1, 4); gz1 += __shfl_xor(gz1, 8);
    gn1 += __shfl_xor(gn1, 1); gn1 += __shfl_xor(gn1, 2); gn1 += __shfl_xor(gn1, 4); gn1 += __shfl_xor(gn1, 8);
    if (l < 2) {
      int b = l;
      float gr = l ? gr1 : gr0, gz = l ? gz1 : gz0, gn = l ? gn1 : gn0;
      float h  = smem[SM_ST + b * 512 + i];   // GRU hidden input (the staged h_in)
      float rr = sigf(smem[SM_GIL + (b * 3 + 0) * 16 + ig] + gr + smem[SM_BHH + 0 + ig]);
      float uu = sigf(smem[SM_GIL + (b * 3 + 1) * 16 + ig] + gz + smem[SM_BHH + 16 + ig]);
      float nn = tanhf_(smem[SM_GIL + (b * 3 + 2) * 16 + ig] + rr * (gn + smem[SM_BHH + 32 + ig]));
      float v = (1.f - uu) * nn + uu * h;
      if (i >= Hc) v = 0.f;
      stgf(wsf + hslotf(2 * g + b, dstSlot) + i, v);
    }
  };

  // ================= phase 0: hv(idx0) = GRU(x0, gs0) =================
  stage2v(OFF_GS0 + (size_t)(2 * g) * 512, OFF_GS0 + (size_t)(2 * g + 1) * 512);
  stagegi(0);
  __syncthreads();
  s2core(0);
  flagbar();

  // ================= scan =================
  for (int index = 1; index < 16; ++index) {
    // ---- phase A: QM-finalize(index-1), PS build, hv0, h_in(s=0) ----
    stage2v(hslotf(2 * g,     trif(index - 1) + index - 1),
            hslotf(2 * g + 1, trif(index - 1) + index - 1));
    if (tid < 32) {
      int b = tid >> 4, j = tid & 15;
      smem[SM_DEP + b * 16 + j] = dep[((size_t)(2 * g + b) * 16 + index) * 16 + j];
    }
    stagegi(index);
    __syncthreads();
    {
      float aq0, am0, aq1, am1;
      s1core(aq0, am0, aq1, am1);
      if (l < 2) {
        float aq = l ? aq1 : aq0, am = l ? am1 : am0;
        smem[SM_QM + ((l * 2 + 0) * 15 + (index - 1)) * 16 + ig] = aq + smem[SM_GC + ig * 16 + (index - 1)];
        smem[SM_QM + ((l * 2 + 1) * 15 + (index - 1)) * 16 + ig] = am + smem[SM_GC + 256 + ig * 16 + (index - 1)];
      }
    }
    __syncthreads();
    if (l < 2) {               // PS backward cumsum, b = l
      float acc = 0.f, gb = smem[SM_GB + ig], mb = smem[SM_MB + ig];
      for (int j = 15; j >= 0; --j) {
        if (j != index) {
          float aa = smem[SM_DEP + l * 16 + j];
          float q, mm;
          if (j < index) { q = smem[SM_QM + ((l * 2 + 0) * 15 + j) * 16 + ig];
                           mm = smem[SM_QM + ((l * 2 + 1) * 15 + j) * 16 + ig]; }
          else           { q = smem[SM_GC + ig * 16 + j];
                           mm = smem[SM_GC + 256 + ig * 16 + j]; }
          float sg = sigf(fmaf(aa, q, gb));
          acc = fmaf(aa * sg, fmaf(aa, mm, mb), acc);
        }
        smem[SM_PS + (l * 16 + ig) * 16 + j] = acc;
      }
    } else if (l < 4) {        // hv0 = gru(x,0), b = l-2
      int b = l - 2;
      float rr = sigf(smem[SM_GIL + (b * 3 + 0) * 16 + ig] + smem[SM_BHH + 0 + ig]);
      float uu = sigf(smem[SM_GIL + (b * 3 + 1) * 16 + ig] + smem[SM_BHH + 16 + ig]);
      float nn = tanhf_(smem[SM_GIL + (b * 3 + 2) * 16 + ig] + rr * smem[SM_BHH + 32 + ig]);
      float v = (1.f - uu) * nn;
      if (i >= Hc) v = 0.f;
      stgf(wsf + hslotf(2 * g + b, trif(index) + 0) + i, v);
    }
    __syncthreads();
    if (l < 2) {               // h_in(s=0): row-index term has ZERO hidden
      int b = l;
      float gb = smem[SM_GB + ig], mb = smem[SM_MB + ig];
      float aI = smem[SM_DEP + b * 16 + index];
      float Qi = smem[SM_GC + ig * 16 + index], Mi = smem[SM_GC + 256 + ig * 16 + index];
      float f = aI * sigf(fmaf(aI, Qi, gb)) * fmaf(aI, Mi, mb);
      float v = smem[SM_PS + (b * 16 + ig) * 16 + (index - 1)] + f;
      if (i >= Hc) v = 0.f;
      stgf(wsf + OFF_HINS + ((size_t)(index * (index - 1) / 2 + 0) * 16 + (2 * g + b)) * 512 + i, v);
    }
    flagbar();

    for (int s = 0; s < index; ++s) {
      // ---- S2(s): hv_{s+1} = GRU(x, h_in_s) ----
      stage2v(OFF_HINS + ((size_t)(index * (index - 1) / 2 + s) * 16 + (2 * g + 0)) * 512,
              OFF_HINS + ((size_t)(index * (index - 1) / 2 + s) * 16 + (2 * g + 1)) * 512);
      __syncthreads();
      s2core(trif(index) + s + 1);
      flagbar();
      if (s + 1 < index) {
        // ---- S1(s+1): h_in = PS[vj] + f(Wg/Wm @ hv_{s+1}) ----
        int ss = s + 1, vj = index - 1 - ss;
        stage2v(hslotf(2 * g, trif(index) + ss), hslotf(2 * g + 1, trif(index) + ss));
        __syncthreads();
        {
          float aq0, am0, aq1, am1;
          s1core(aq0, am0, aq1, am1);
          if (l < 2) {
            int b = l;
            float aq = l ? aq1 : aq0, am = l ? am1 : am0;
            float gb = smem[SM_GB + ig], mb = smem[SM_MB + ig];
            float aI = smem[SM_DEP + b * 16 + index];
            float Qi = aq + smem[SM_GC + ig * 16 + index];
            float Mi = am + smem[SM_GC + 256 + ig * 16 + index];
            float f = aI * sigf(fmaf(aI, Qi, gb)) * fmaf(aI, Mi, mb);
            float v = smem[SM_PS + (b * 16 + ig) * 16 + vj] + f;
            if (i >= Hc) v = 0.f;
            stgf(wsf + OFF_HINS + ((size_t)(index * (index - 1) / 2 + ss) * 16 + (2 * g + b)) * 512 + i, v);
          }
        }
        flagbar();
      }
    }
  }
}

// ================= k2: deferred edges + node encodings (own regalloc) ==========
__global__ __launch_bounds__(256, 1) void k2_fin(KArgs a) {
  const int blk = blockIdx.x, tid = threadIdx.x;
  float* wsf = a.wsf;
  unsigned* FLG = (unsigned*)a.wsf + WS_FLOATS;
  unsigned* F1F = FLG + N_FLG;

  __shared__ float smem[F_TOT];
  const int b = blk >> 4, rs = blk & 15;
  const int il = tid >> 3, l8 = tid & 7;
  float4* lds4 = (float4*)smem;

  // ---- F1a: Bhj = W_hj @ nhs_j (j<15) -> LDS ----
  for (int t = tid; t < 2048; t += 256) {
    int j = t >> 7, k4 = t & 127;
    float4 v = {0.f, 0.f, 0.f, 0.f};
    if (j < 15) v = ((const float4*)(wsf + hslotf(b, trif(j) + j)))[k4];
    lds4[t] = v;
  }
  __syncthreads();
  for (int half = 0; half < 2; ++half) {
    int jbase = half * 8;
    float acc[4][8];
    #pragma unroll
    for (int q = 0; q < 4; ++q)
      #pragma unroll
      for (int j = 0; j < 8; ++j) acc[q][j] = 0.f;
    int rbase = rs * 126 + il * 4;
    #pragma unroll
    for (int s2 = 0; s2 < 16; ++s2) {
      int k4 = s2 * 8 + l8;
      float4 h4v[8];
      #pragma unroll
      for (int j = 0; j < 8; ++j) h4v[j] = lds4[(jbase + j) * 128 + k4];
      #pragma unroll
      for (int q = 0; q < 4; ++q) {
        float4 wv = ((const float4*)(wsf + OFF_WHJ))[(size_t)(rbase + q) * 128 + k4];
        #pragma unroll
        for (int j = 0; j < 8; ++j) {
          acc[q][j] = fmaf(wv.x, h4v[j].x, acc[q][j]); acc[q][j] = fmaf(wv.y, h4v[j].y, acc[q][j]);
          acc[q][j] = fmaf(wv.z, h4v[j].z, acc[q][j]); acc[q][j] = fmaf(wv.w, h4v[j].w, acc[q][j]);
        }
      }
    }
    #pragma unroll
    for (int q = 0; q < 4; ++q) {
      bool rowok = (il * 4 + q < 126) && (rbase + q < 2004);
      #pragma unroll
      for (int j = 0; j < 8; ++j) {
        float v = acc[q][j];
        v += __shfl_xor(v, 1); v += __shfl_xor(v, 2); v += __shfl_xor(v, 4);
        if (l8 == 0 && rowok && (jbase + j) < 15)
          smem[F_BHJ + (jbase + j) * 128 + il * 4 + q] = v;
      }
    }
  }
  __syncthreads();
  // ---- F1b: TBUF = relu(av1 @ graph_state list) ----
  for (int t = tid; t < 2048; t += 256) {
    int idx = t >> 7, k4 = t & 127;
    const float4* src = (idx == 0)
      ? ((const float4*)(wsf + OFF_GS0 + (size_t)b * 512))
      : ((const float4*)(wsf + hslotf(b, trif(idx - 1) + idx - 1)));
    lds4[t] = src[k4];
  }
  __syncthreads();
  const float* av1b = a.in[6];
  for (int half = 0; half < 2; ++half) {
    int jbase = half * 8;
    float acc[2][8];
    #pragma unroll
    for (int q = 0; q < 2; ++q)
      #pragma unroll
      for (int j = 0; j < 8; ++j) acc[q][j] = 0.f;
    int rbase = rs * 63 + il * 2;
    #pragma unroll
    for (int s2 = 0; s2 < 16; ++s2) {
      int k4 = s2 * 8 + l8;
      float4 h4v[8];
      #pragma unroll
      for (int j = 0; j < 8; ++j) h4v[j] = lds4[(jbase + j) * 128 + k4];
      #pragma unroll
      for (int q = 0; q < 2; ++q) {
        float4 wv = ((const float4*)(wsf + OFF_WAV))[(size_t)(rbase + q) * 128 + k4];
        #pragma unroll
        for (int j = 0; j < 8; ++j) {
          acc[q][j] = fmaf(wv.x, h4v[j].x, acc[q][j]); acc[q][j] = fmaf(wv.y, h4v[j].y, acc[q][j]);
          acc[q][j] = fmaf(wv.z, h4v[j].z, acc[q][j]); acc[q][j] = fmaf(wv.w, h4v[j].w, acc[q][j]);
        }
      }
    }
    #pragma unroll
    for (int q = 0; q < 2; ++q) {
      int r = rbase + q;
      bool rowok = (il * 2 + q < 63) && (r < 1002);
      float b1 = rowok ? av1b[r] : 0.f;
      #pragma unroll
      for (int j = 0; j < 8; ++j) {
        float v = acc[q][j];
        v += __shfl_xor(v, 1); v += __shfl_xor(v, 2); v += __shfl_xor(v, 4);
        if (l8 == 0 && rowok)
          stgf(wsf + OFF_TBUF + ((size_t)b * 16 + jbase + j) * 1024 + r, fmaxf(v + b1, 0.f));
      }
    }
  }
  __syncthreads();
  if (tid == 0)
    __hip_atomic_store(F1F + b * 16 + rs, 1u, __ATOMIC_RELAXED, __HIP_MEMORY_SCOPE_AGENT);

  // ---- F2: all 120 edges per batch ----
  const float* ae1b = a.in[10]; const float* ae2w = a.in[11]; const float* ae2b = a.in[12];
  for (int chunk = 0; chunk < 15; ++chunk) {
    int idxs[8], vjs[8]; bool tval[8];
    #pragma unroll
    for (int j = 0; j < 8; ++j) {
      int e = chunk * 8 + j;
      if (e < 120) {
        int ix = 1, rem = e;
        while (rem >= ix) { rem -= ix; ++ix; }
        idxs[j] = ix; vjs[j] = rem; tval[j] = true;
      } else { idxs[j] = 1; vjs[j] = 0; tval[j] = false; }
    }
    __syncthreads();
    for (int t = tid; t < 1024; t += 256) {
      int sl = t >> 7, k4 = t & 127;
      int sE = idxs[sl] - 1 - vjs[sl];
      lds4[t] = ((const float4*)(wsf + hslotf(b, trif(idxs[sl]) + sE)))[k4];
    }
    __syncthreads();
    float part[8];
    #pragma unroll
    for (int j = 0; j < 8; ++j) part[j] = 0.f;
    int rbase = rs * 126 + il * 4;
    float acc[4][8];
    #pragma unroll
    for (int q = 0; q < 4; ++q)
      #pragma unroll
      for (int j = 0; j < 8; ++j) acc[q][j] = 0.f;
    #pragma unroll
    for (int s2 = 0; s2 < 16; ++s2) {
      int k4 = s2 * 8 + l8;
      float4 h4v[8];
      #pragma unroll
      for (int j = 0; j < 8; ++j) h4v[j] = lds4[j * 128 + k4];
      #pragma unroll
      for (int q = 0; q < 4; ++q) {
        float4 wv = ((const float4*)(wsf + OFF_WHV))[(size_t)(rbase + q) * 128 + k4];
        #pragma unroll
        for (int j = 0; j < 8; ++j) {
          acc[q][j] = fmaf(wv.x, h4v[j].x, acc[q][j]); acc[q][j] = fmaf(wv.y, h4v[j].y, acc[q][j]);
          acc[q][j] = fmaf(wv.z, h4v[j].z, acc[q][j]); acc[q][j] = fmaf(wv.w, h4v[j].w, acc[q][j]);
        }
      }
    }
    #pragma unroll
    for (int q = 0; q < 4; ++q) {
      int r = rbase + q;
      bool rowok = (il * 4 + q < 126) && (r < 2004);
      float aer = rowok ? ae2w[r] : 0.f;
      float b1r = rowok ? ae1b[r] : 0.f;
      #pragma unroll
      for (int j = 0; j < 8; ++j) {
        float v = acc[q][j];
        v += __shfl_xor(v, 1); v += __shfl_xor(v, 2); v += __shfl_xor(v, 4);
        if (l8 == 0 && rowok && tval[j]) {
          float bh = smem[F_BHJ + vjs[j] * 128 + il * 4 + q];
          part[j] = fmaf(aer, fmaxf(v + bh + b1r, 0.f), part[j]);
        }
      }
    }
    if (l8 == 0) {
      #pragma unroll
      for (int j = 0; j < 8; ++j) smem[F_RED + il * 8 + j] = part[j];
    }
    __syncthreads();
    if (tid < 8) {
      float v = 0.f;
      for (int q = 0; q < 32; ++q) v += smem[F_RED + q * 8 + tid];
      if (rs == 0) v += ae2b[0];
      if (tval[tid])
        atomicAdd(a.out + ((size_t)b * 16 + idxs[tid]) * 16 + vjs[tid], v);
    }
    __syncthreads();
  }
  // ---- F3: gen_node_encoding[(b, rs)] ----
  if (tid < 16) {
    unsigned* p = F1F + b * 16 + tid;
    while (__hip_atomic_load(p, __ATOMIC_RELAXED, __HIP_MEMORY_SCOPE_AGENT) != 1u)
      __builtin_amdgcn_s_sleep(2);
  }
  __syncthreads();
  {
    const float* av2w = a.in[7]; const float* av2b = a.in[8];
    const float* tb = wsf + OFF_TBUF + ((size_t)b * 16 + rs) * 1024;
    float accn[10];
    #pragma unroll
    for (int c = 0; c < 10; ++c) accn[c] = 0.f;
    for (int r = tid; r < 1002; r += 256) {
      float tv = tb[r];
      #pragma unroll
      for (int c = 0; c < 10; ++c) accn[c] = fmaf(av2w[(size_t)c * 1002 + r], tv, accn[c]);
    }
    #pragma unroll
    for (int c = 0; c < 10; ++c) {
      float v = accn[c];
      for (int m2 = 1; m2 < 64; m2 <<= 1) v += __shfl_xor(v, m2);
      if ((tid & 63) == 0) smem[F_RED + (tid >> 6) * 10 + c] = v;
    }
    __syncthreads();
    if (tid == 0) {
      for (int c = 0; c < 10; ++c) {
        float v = av2b[c] + smem[F_RED + c] + smem[F_RED + 10 + c] + smem[F_RED + 20 + c] + smem[F_RED + 30 + c];
        stgf(a.out + 4096 + ((size_t)b * 16 + rs) * 10 + c, v);
      }
    }
  }
}

extern "C" void kernel_launch(void* const* d_in, const int* in_sizes, int n_in,
                              void* d_out, int out_size, void* d_ws, size_t ws_size,
                              hipStream_t stream) {
  (void)in_sizes; (void)n_in; (void)out_size;
  if (ws_size < WS_NEED) return;   // fail loudly via validation
  KArgs a;
  for (int k = 0; k < 21; ++k) a.in[k] = (const float*)d_in[k];
  a.out = (float*)d_out;
  a.wsf = (float*)d_ws;
  k0_init<<<256, 256, 0, stream>>>(a);
  k1_scan<<<256, 256, 0, stream>>>(a);
  k2_fin <<<256, 256, 0, stream>>>(a);
}

// Round 6
// 1330.051 us; speedup vs baseline: 3.7513x; 2.3941x over previous
//
#include <hip/hip_runtime.h>

#define DEVFN static __device__ __forceinline__

namespace {
constexpr int Hc = 501, Gc = 517;
// ---- workspace float offsets (WHV/WHJ/WAV slots now dead: k2 reads d_in directly) ----
constexpr size_t OFF_WGP = 0;                               // [512][512] gate_w[:, :H] padded
constexpr size_t OFF_WMP = OFF_WGP + (size_t)512 * 512;     // map_w[:, :H]
constexpr size_t OFF_WHP = OFF_WMP + (size_t)512 * 512;     // w_hh packed [i][3][512]
constexpr size_t OFF_WHV = OFF_WHP + (size_t)512 * 1536;    // (dead)
constexpr size_t OFF_WHJ = OFF_WHV + (size_t)2048 * 512;    // (dead)
constexpr size_t OFF_WAV = OFF_WHJ + (size_t)2048 * 512;    // (dead)
constexpr size_t OFF_GCOL= OFF_WAV + (size_t)1024 * 512;    // gate_w[:, H+j] [512][16]
constexpr size_t OFF_MCOL= OFF_GCOL + (size_t)512 * 16;
constexpr size_t OFF_GI  = OFF_MCOL + (size_t)512 * 16;     // [16][16][1536]
constexpr size_t OFF_GS0 = OFF_GI  + (size_t)16 * 16 * 1536;// [16][512]
constexpr size_t OFF_HSEQ= OFF_GS0 + (size_t)16 * 512;      // [16 b][136 slot][512]
constexpr size_t OFF_HINS= OFF_HSEQ+ (size_t)16 * 136 * 512;// [120 slot][16 b][512]
constexpr size_t OFF_TBUF= OFF_HINS+ (size_t)120 * 16 * 512;// [16 b][16 idx][1024]
constexpr size_t WS_FLOATS=OFF_TBUF+ (size_t)16 * 16 * 1024;
constexpr size_t N_FLG   = (size_t)8 * 256 * 32;            // [group][pid][member]
constexpr size_t WS_NEED = (WS_FLOATS + N_FLG + 512 + 64) * 4;

// ---- k1 LDS float offsets ----
constexpr int SM_WHH = 0;       // 16*3*512 = 24576
constexpr int SM_ST  = 24576;   // 2*512 staging
constexpr int SM_QM  = 25600;   // [b*2+qm][j<15][ig]  2*2*15*16 = 960
constexpr int SM_PS  = 26560;   // [b][ig][vj] 512
constexpr int SM_GC  = 27072;   // [q/m][ig][j] 512
constexpr int SM_GIL = 27584;   // [b][r][ig] 96
constexpr int SM_BHH = 27680;   // [r][ig] 48
constexpr int SM_GB  = 27728;   // 16
constexpr int SM_MB  = 27744;   // 16
constexpr int SM_DEP = 27760;   // [b][j] 32
constexpr int SM_TOT = 27792;
// ---- k2 LDS float offsets ----
constexpr int F_BHJ = 8192;     // [j<15][128]  (after 16x512 staging)
constexpr int F_RED = 10112;    // 260
constexpr int F_TOT = 10376;
} // namespace

DEVFN float sigf(float x)  { return 1.0f / (1.0f + __expf(-x)); }
DEVFN float tanhf_(float x){ float e2 = __expf(2.0f * x); return 1.0f - 2.0f / (e2 + 1.0f); }
DEVFN void  stgf(float* p, float v) { __hip_atomic_store(p, v, __ATOMIC_RELAXED, __HIP_MEMORY_SCOPE_AGENT); }
DEVFN size_t hslotf(int b, int slot) { return OFF_HSEQ + ((size_t)b * 136 + slot) * 512; }
DEVFN int trif(int idx) { return idx * (idx + 1) / 2; }

struct KArgs {
  const float* in[21];
  float* out;
  float* wsf;
};

// zero the pad elements (>=501) of a staged 512-float4 slot value
DEVFN float4 maskpad(float4 v, int k4) {
  if (k4 == 125) { v.y = 0.f; v.z = 0.f; v.w = 0.f; }
  else if (k4 > 125) { v.x = v.y = v.z = v.w = 0.f; }
  return v;
}

// ================= init kernel: repack scan weights, gi, gs0, zero out/flags ==========
__global__ __launch_bounds__(256) void k0_init(KArgs a) {
  const float* z    = a.in[0];  const float* enc  = a.in[2];
  const float* lin1w= a.in[3];  const float* lin1b= a.in[4];
  const float* gatew= a.in[13]; const float* mapw = a.in[15];
  const float* wih  = a.in[17]; const float* bih  = a.in[18];
  const float* whh  = a.in[19];
  float* wsf = a.wsf;
  const int gtid = blockIdx.x * 256 + threadIdx.x;
  const int NTH = 256 * 256;

  for (size_t t = gtid; t < (size_t)512 * 512; t += NTH) {
    int i = t >> 9, k = t & 511;
    bool ok = (i < Hc && k < Hc);
    wsf[OFF_WGP + t] = ok ? gatew[(size_t)i * Gc + k] : 0.f;
    wsf[OFF_WMP + t] = ok ? mapw [(size_t)i * Gc + k] : 0.f;
  }
  for (size_t t = gtid; t < (size_t)512 * 1536; t += NTH) {
    int i = t / 1536, rk = t % 1536, r = rk >> 9, k = rk & 511;
    wsf[OFF_WHP + t] = (i < Hc && k < Hc) ? whh[((size_t)r * Hc + i) * Hc + k] : 0.f;
  }
  for (size_t t = gtid; t < (size_t)512 * 16; t += NTH) {
    int i = t >> 4, j = t & 15;
    wsf[OFF_GCOL + t] = (i < Hc) ? gatew[(size_t)i * Gc + Hc + j] : 0.f;
    wsf[OFF_MCOL + t] = (i < Hc) ? mapw [(size_t)i * Gc + Hc + j] : 0.f;
  }
  for (size_t t = gtid; t < (size_t)16 * 16 * 1503; t += NTH) {
    int r = t % 1503; size_t bi = t / 1503;
    float acc = bih[r];
    const float* x = enc + bi * 10;
    const float* w = wih + (size_t)r * 10;
    #pragma unroll
    for (int c = 0; c < 10; ++c) acc = fmaf(w[c], x[c], acc);
    wsf[OFF_GI + bi * 1536 + r] = acc;
  }
  for (size_t t = gtid; t < (size_t)16 * 512; t += NTH) {
    int b = t >> 9, i = t & 511;
    float v = 0.f;
    if (i < Hc) {
      float acc = lin1b[i];
      const float* zz = z + (size_t)b * 56;
      const float* w  = lin1w + (size_t)i * 56;
      for (int k = 0; k < 56; ++k) acc = fmaf(w[k], zz[k], acc);
      v = acc;
    }
    wsf[OFF_GS0 + t] = v;
  }
  for (size_t t = gtid; t < 4096; t += NTH) a.out[t] = 0.f;   // gen_dep zero (atomics)
  unsigned* FLG = (unsigned*)a.wsf + WS_FLOATS;
  for (size_t t = gtid; t < N_FLG + 512; t += NTH) FLG[t] = 0u;
}

// ================= k1: persistent scan kernel (unchanged from R5) ==========
__global__ __launch_bounds__(256, 1) void k1_scan(KArgs a) {
  const int blk = blockIdx.x, tid = threadIdx.x;
  const int g = blk >> 5, m = blk & 31;        // group (2 batches), member
  const int ig = tid >> 4, l = tid & 15;       // i-subgroup, k-lane
  const int i = m * 16 + ig;                   // owned row
  float* wsf = a.wsf;
  unsigned* FLG = (unsigned*)a.wsf + WS_FLOATS;
  const float* dep  = a.in[1];
  const float* gateb= a.in[14]; const float* mapb = a.in[16];
  const float* bhh  = a.in[20];

  __shared__ float smem[SM_TOT];
  int pid = 0;

  {
    float4* d = (float4*)smem;
    const float4* s = ((const float4*)(wsf + OFF_WHP)) + (size_t)m * 6144;
    for (int t = tid; t < 6144; t += 256) d[t] = s[t];
    for (int t = tid; t < 512; t += 256) {
      int q = t >> 8, r2 = t & 255, ii = r2 >> 4, j = r2 & 15;
      smem[SM_GC + t] = wsf[(q ? OFF_MCOL : OFF_GCOL) + (size_t)(m * 16 + ii) * 16 + j];
    }
    if (tid < 16) {
      int iG = m * 16 + tid;
      smem[SM_GB + tid] = (iG < Hc) ? gateb[iG] : 0.f;
      smem[SM_MB + tid] = (iG < Hc) ? mapb[iG]  : 0.f;
    }
    if (tid < 48) {
      int r = tid >> 4, ii = tid & 15, iG = m * 16 + ii;
      smem[SM_BHH + tid] = (iG < Hc) ? bhh[r * Hc + iG] : 0.f;
    }
  }
  float4 wgr[8], wmr[8];
  {
    const float4* pg = ((const float4*)(wsf + OFF_WGP)) + (size_t)i * 128;
    const float4* pm = ((const float4*)(wsf + OFF_WMP)) + (size_t)i * 128;
    #pragma unroll
    for (int t = 0; t < 8; ++t) { wgr[t] = pg[t * 16 + l]; wmr[t] = pm[t * 16 + l]; }
  }
  __syncthreads();

  auto flagbar = [&]() {
    __syncthreads();
    if (tid == 0)
      __hip_atomic_store(FLG + ((size_t)g * 256 + pid) * 32 + m, (unsigned)(pid + 1),
                         __ATOMIC_RELAXED, __HIP_MEMORY_SCOPE_AGENT);
    if (tid < 32) {
      unsigned* p = FLG + ((size_t)g * 256 + pid) * 32 + tid;
      while (__hip_atomic_load(p, __ATOMIC_RELAXED, __HIP_MEMORY_SCOPE_AGENT) != (unsigned)(pid + 1))
        __builtin_amdgcn_s_sleep(2);
    }
    __syncthreads();
    ++pid;
  };

  auto stage2v = [&](size_t o0, size_t o1) {
    float4* d = (float4*)(smem + SM_ST);
    if (tid < 128) d[tid] = ((const float4*)(wsf + o0))[tid];
    else           d[tid] = ((const float4*)(wsf + o1))[tid - 128];
  };
  auto stagegi = [&](int index) {
    if (tid >= 64 && tid < 160) {
      int t = tid - 64, b = t / 48, r = (t / 16) % 3, ii = t & 15, iG = m * 16 + ii;
      smem[SM_GIL + (b * 3 + r) * 16 + ii] =
        (iG < Hc) ? wsf[OFF_GI + ((size_t)(2 * g + b) * 16 + index) * 1536 + (size_t)r * Hc + iG] : 0.f;
    }
  };
  auto s1core = [&](float& aq0, float& am0, float& aq1, float& am1) {
    const float4* h0 = (const float4*)(smem + SM_ST);
    const float4* h1 = (const float4*)(smem + SM_ST + 512);
    float q0 = 0.f, m0 = 0.f, q1 = 0.f, m1 = 0.f;
    #pragma unroll
    for (int t = 0; t < 8; ++t) {
      int k4 = t * 16 + l;
      float4 a0 = h0[k4], a1 = h1[k4];
      q0 = fmaf(wgr[t].x, a0.x, q0); q0 = fmaf(wgr[t].y, a0.y, q0);
      q0 = fmaf(wgr[t].z, a0.z, q0); q0 = fmaf(wgr[t].w, a0.w, q0);
      m0 = fmaf(wmr[t].x, a0.x, m0); m0 = fmaf(wmr[t].y, a0.y, m0);
      m0 = fmaf(wmr[t].z, a0.z, m0); m0 = fmaf(wmr[t].w, a0.w, m0);
      q1 = fmaf(wgr[t].x, a1.x, q1); q1 = fmaf(wgr[t].y, a1.y, q1);
      q1 = fmaf(wgr[t].z, a1.z, q1); q1 = fmaf(wgr[t].w, a1.w, q1);
      m1 = fmaf(wmr[t].x, a1.x, m1); m1 = fmaf(wmr[t].y, a1.y, m1);
      m1 = fmaf(wmr[t].z, a1.z, m1); m1 = fmaf(wmr[t].w, a1.w, m1);
    }
    q0 += __shfl_xor(q0, 1); q0 += __shfl_xor(q0, 2); q0 += __shfl_xor(q0, 4); q0 += __shfl_xor(q0, 8);
    m0 += __shfl_xor(m0, 1); m0 += __shfl_xor(m0, 2); m0 += __shfl_xor(m0, 4); m0 += __shfl_xor(m0, 8);
    q1 += __shfl_xor(q1, 1); q1 += __shfl_xor(q1, 2); q1 += __shfl_xor(q1, 4); q1 += __shfl_xor(q1, 8);
    m1 += __shfl_xor(m1, 1); m1 += __shfl_xor(m1, 2); m1 += __shfl_xor(m1, 4); m1 += __shfl_xor(m1, 8);
    aq0 = q0; am0 = m0; aq1 = q1; am1 = m1;
  };
  auto s2core = [&](int dstSlot) {
    const float4* W  = ((const float4*)smem) + ig * 384;
    const float4* h0 = (const float4*)(smem + SM_ST);
    const float4* h1 = (const float4*)(smem + SM_ST + 512);
    float gr0 = 0.f, gz0 = 0.f, gn0 = 0.f, gr1 = 0.f, gz1 = 0.f, gn1 = 0.f;
    #pragma unroll
    for (int t = 0; t < 8; ++t) {
      int k4 = t * 16 + l;
      float4 hv0 = h0[k4], hv1 = h1[k4];
      float4 a0 = W[k4], a1 = W[128 + k4], a2 = W[256 + k4];
      gr0 = fmaf(a0.x, hv0.x, gr0); gr0 = fmaf(a0.y, hv0.y, gr0); gr0 = fmaf(a0.z, hv0.z, gr0); gr0 = fmaf(a0.w, hv0.w, gr0);
      gz0 = fmaf(a1.x, hv0.x, gz0); gz0 = fmaf(a1.y, hv0.y, gz0); gz0 = fmaf(a1.z, hv0.z, gz0); gz0 = fmaf(a1.w, hv0.w, gz0);
      gn0 = fmaf(a2.x, hv0.x, gn0); gn0 = fmaf(a2.y, hv0.y, gn0); gn0 = fmaf(a2.z, hv0.z, gn0); gn0 = fmaf(a2.w, hv0.w, gn0);
      gr1 = fmaf(a0.x, hv1.x, gr1); gr1 = fmaf(a0.y, hv1.y, gr1); gr1 = fmaf(a0.z, hv1.z, gr1); gr1 = fmaf(a0.w, hv1.w, gr1);
      gz1 = fmaf(a1.x, hv1.x, gz1); gz1 = fmaf(a1.y, hv1.y, gz1); gz1 = fmaf(a1.z, hv1.z, gz1); gz1 = fmaf(a1.w, hv1.w, gz1);
      gn1 = fmaf(a2.x, hv1.x, gn1); gn1 = fmaf(a2.y, hv1.y, gn1); gn1 = fmaf(a2.z, hv1.z, gn1); gn1 = fmaf(a2.w, hv1.w, gn1);
    }
    gr0 += __shfl_xor(gr0, 1); gr0 += __shfl_xor(gr0, 2); gr0 += __shfl_xor(gr0, 4); gr0 += __shfl_xor(gr0, 8);
    gz0 += __shfl_xor(gz0, 1); gz0 += __shfl_xor(gz0, 2); gz0 += __shfl_xor(gz0, 4); gz0 += __shfl_xor(gz0, 8);
    gn0 += __shfl_xor(gn0, 1); gn0 += __shfl_xor(gn0, 2); gn0 += __shfl_xor(gn0, 4); gn0 += __shfl_xor(gn0, 8);
    gr1 += __shfl_xor(gr1, 1); gr1 += __shfl_xor(gr1, 2); gr1 += __shfl_xor(gr1, 4); gr1 += __shfl_xor(gr1, 8);
    gz1 += __shfl_xor(gz1, 1); gz1 += __shfl_xor(gz1, 2); gz1 += __shfl_xor(gz1, 4); gz1 += __shfl_xor(gz1, 8);
    gn1 += __shfl_xor(gn1, 1); gn1 += __shfl_xor(gn1, 2); gn1 += __shfl_xor(gn1, 4); gn1 += __shfl_xor(gn1, 8);
    if (l < 2) {
      int b = l;
      float gr = l ? gr1 : gr0, gz = l ? gz1 : gz0, gn = l ? gn1 : gn0;
      float h  = smem[SM_ST + b * 512 + i];
      float rr = sigf(smem[SM_GIL + (b * 3 + 0) * 16 + ig] + gr + smem[SM_BHH + 0 + ig]);
      float uu = sigf(smem[SM_GIL + (b * 3 + 1) * 16 + ig] + gz + smem[SM_BHH + 16 + ig]);
      float nn = tanhf_(smem[SM_GIL + (b * 3 + 2) * 16 + ig] + rr * (gn + smem[SM_BHH + 32 + ig]));
      float v = (1.f - uu) * nn + uu * h;
      if (i >= Hc) v = 0.f;
      stgf(wsf + hslotf(2 * g + b, dstSlot) + i, v);
    }
  };

  stage2v(OFF_GS0 + (size_t)(2 * g) * 512, OFF_GS0 + (size_t)(2 * g + 1) * 512);
  stagegi(0);
  __syncthreads();
  s2core(0);
  flagbar();

  for (int index = 1; index < 16; ++index) {
    stage2v(hslotf(2 * g,     trif(index - 1) + index - 1),
            hslotf(2 * g + 1, trif(index - 1) + index - 1));
    if (tid < 32) {
      int b = tid >> 4, j = tid & 15;
      smem[SM_DEP + b * 16 + j] = dep[((size_t)(2 * g + b) * 16 + index) * 16 + j];
    }
    stagegi(index);
    __syncthreads();
    {
      float aq0, am0, aq1, am1;
      s1core(aq0, am0, aq1, am1);
      if (l < 2) {
        float aq = l ? aq1 : aq0, am = l ? am1 : am0;
        smem[SM_QM + ((l * 2 + 0) * 15 + (index - 1)) * 16 + ig] = aq + smem[SM_GC + ig * 16 + (index - 1)];
        smem[SM_QM + ((l * 2 + 1) * 15 + (index - 1)) * 16 + ig] = am + smem[SM_GC + 256 + ig * 16 + (index - 1)];
      }
    }
    __syncthreads();
    if (l < 2) {
      float acc = 0.f, gb = smem[SM_GB + ig], mb = smem[SM_MB + ig];
      for (int j = 15; j >= 0; --j) {
        if (j != index) {
          float aa = smem[SM_DEP + l * 16 + j];
          float q, mm;
          if (j < index) { q = smem[SM_QM + ((l * 2 + 0) * 15 + j) * 16 + ig];
                           mm = smem[SM_QM + ((l * 2 + 1) * 15 + j) * 16 + ig]; }
          else           { q = smem[SM_GC + ig * 16 + j];
                           mm = smem[SM_GC + 256 + ig * 16 + j]; }
          float sg = sigf(fmaf(aa, q, gb));
          acc = fmaf(aa * sg, fmaf(aa, mm, mb), acc);
        }
        smem[SM_PS + (l * 16 + ig) * 16 + j] = acc;
      }
    } else if (l < 4) {
      int b = l - 2;
      float rr = sigf(smem[SM_GIL + (b * 3 + 0) * 16 + ig] + smem[SM_BHH + 0 + ig]);
      float uu = sigf(smem[SM_GIL + (b * 3 + 1) * 16 + ig] + smem[SM_BHH + 16 + ig]);
      float nn = tanhf_(smem[SM_GIL + (b * 3 + 2) * 16 + ig] + rr * smem[SM_BHH + 32 + ig]);
      float v = (1.f - uu) * nn;
      if (i >= Hc) v = 0.f;
      stgf(wsf + hslotf(2 * g + b, trif(index) + 0) + i, v);
    }
    __syncthreads();
    if (l < 2) {
      int b = l;
      float gb = smem[SM_GB + ig], mb = smem[SM_MB + ig];
      float aI = smem[SM_DEP + b * 16 + index];
      float Qi = smem[SM_GC + ig * 16 + index], Mi = smem[SM_GC + 256 + ig * 16 + index];
      float f = aI * sigf(fmaf(aI, Qi, gb)) * fmaf(aI, Mi, mb);
      float v = smem[SM_PS + (b * 16 + ig) * 16 + (index - 1)] + f;
      if (i >= Hc) v = 0.f;
      stgf(wsf + OFF_HINS + ((size_t)(index * (index - 1) / 2 + 0) * 16 + (2 * g + b)) * 512 + i, v);
    }
    flagbar();

    for (int s = 0; s < index; ++s) {
      stage2v(OFF_HINS + ((size_t)(index * (index - 1) / 2 + s) * 16 + (2 * g + 0)) * 512,
              OFF_HINS + ((size_t)(index * (index - 1) / 2 + s) * 16 + (2 * g + 1)) * 512);
      __syncthreads();
      s2core(trif(index) + s + 1);
      flagbar();
      if (s + 1 < index) {
        int ss = s + 1, vj = index - 1 - ss;
        stage2v(hslotf(2 * g, trif(index) + ss), hslotf(2 * g + 1, trif(index) + ss));
        __syncthreads();
        {
          float aq0, am0, aq1, am1;
          s1core(aq0, am0, aq1, am1);
          if (l < 2) {
            int b = l;
            float aq = l ? aq1 : aq0, am = l ? am1 : am0;
            float gb = smem[SM_GB + ig], mb = smem[SM_MB + ig];
            float aI = smem[SM_DEP + b * 16 + index];
            float Qi = aq + smem[SM_GC + ig * 16 + index];
            float Mi = am + smem[SM_GC + 256 + ig * 16 + index];
            float f = aI * sigf(fmaf(aI, Qi, gb)) * fmaf(aI, Mi, mb);
            float v = smem[SM_PS + (b * 16 + ig) * 16 + vj] + f;
            if (i >= Hc) v = 0.f;
            stgf(wsf + OFF_HINS + ((size_t)(index * (index - 1) / 2 + ss) * 16 + (2 * g + b)) * 512 + i, v);
          }
        }
        flagbar();
      }
    }
  }
}

// ================= k2: deferred edges + node encodings — weights from d_in (L2-cached) ==========
__global__ __launch_bounds__(256, 1) void k2_fin(KArgs a) {
  const int blk = blockIdx.x, tid = threadIdx.x;
  float* wsf = a.wsf;
  unsigned* FLG = (unsigned*)a.wsf + WS_FLOATS;
  unsigned* F1F = FLG + N_FLG;
  const float* ae1w = a.in[9];   // [2004][1002] row-major, cached
  const float* av1w = a.in[5];   // [1002][501]

  __shared__ float smem[F_TOT];
  const int b = blk >> 4, rs = blk & 15;
  const int il = tid >> 3, l8 = tid & 7;
  float4* lds4 = (float4*)smem;

  // ---- F1a: Bhj[r] = sum_k ae1w[r][501+k] * nhs_j[k] ----
  for (int t = tid; t < 2048; t += 256) {
    int j = t >> 7, k4 = t & 127;
    float4 v = {0.f, 0.f, 0.f, 0.f};
    if (j < 15) v = maskpad(((const float4*)(wsf + hslotf(b, trif(j) + j)))[k4], k4);
    lds4[t] = v;
  }
  __syncthreads();
  {
    const int rbase = rs * 126 + il * 4;
    for (int half = 0; half < 2; ++half) {
      int jbase = half * 8;
      float acc[4][8];
      #pragma unroll
      for (int q = 0; q < 4; ++q)
        #pragma unroll
        for (int j = 0; j < 8; ++j) acc[q][j] = 0.f;
      for (int s = 0; s < 63; ++s) {
        int k = s * 8 + l8;
        if (k < 501) {
          float w[4];
          #pragma unroll
          for (int q = 0; q < 4; ++q)
            w[q] = (rbase + q < 2004) ? ae1w[(size_t)(rbase + q) * 1002 + 501 + k] : 0.f;
          float hv[8];
          #pragma unroll
          for (int j = 0; j < 8; ++j) hv[j] = smem[(jbase + j) * 512 + k];
          #pragma unroll
          for (int q = 0; q < 4; ++q)
            #pragma unroll
            for (int j = 0; j < 8; ++j) acc[q][j] = fmaf(w[q], hv[j], acc[q][j]);
        }
      }
      #pragma unroll
      for (int q = 0; q < 4; ++q) {
        bool rowok = (il * 4 + q < 126) && (rbase + q < 2004);
        #pragma unroll
        for (int j = 0; j < 8; ++j) {
          float v = acc[q][j];
          v += __shfl_xor(v, 1); v += __shfl_xor(v, 2); v += __shfl_xor(v, 4);
          if (l8 == 0 && rowok && (jbase + j) < 15)
            smem[F_BHJ + (jbase + j) * 128 + il * 4 + q] = v;
        }
      }
    }
  }
  __syncthreads();
  // ---- F1b: TBUF = relu(av1w @ graph_state list + b) ----
  for (int t = tid; t < 2048; t += 256) {
    int idx = t >> 7, k4 = t & 127;
    const float4* src = (idx == 0)
      ? ((const float4*)(wsf + OFF_GS0 + (size_t)b * 512))
      : ((const float4*)(wsf + hslotf(b, trif(idx - 1) + idx - 1)));
    lds4[t] = maskpad(src[k4], k4);
  }
  __syncthreads();
  {
    const float* av1b = a.in[6];
    const int rbase = rs * 63 + il * 2;
    for (int half = 0; half < 2; ++half) {
      int jbase = half * 8;
      float acc[2][8];
      #pragma unroll
      for (int q = 0; q < 2; ++q)
        #pragma unroll
        for (int j = 0; j < 8; ++j) acc[q][j] = 0.f;
      for (int s = 0; s < 63; ++s) {
        int k = s * 8 + l8;
        if (k < 501) {
          float w[2];
          #pragma unroll
          for (int q = 0; q < 2; ++q)
            w[q] = (rbase + q < 1002) ? av1w[(size_t)(rbase + q) * 501 + k] : 0.f;
          float hv[8];
          #pragma unroll
          for (int j = 0; j < 8; ++j) hv[j] = smem[(jbase + j) * 512 + k];
          #pragma unroll
          for (int q = 0; q < 2; ++q)
            #pragma unroll
            for (int j = 0; j < 8; ++j) acc[q][j] = fmaf(w[q], hv[j], acc[q][j]);
        }
      }
      #pragma unroll
      for (int q = 0; q < 2; ++q) {
        int r = rbase + q;
        bool rowok = (il * 2 + q < 63) && (r < 1002);
        float b1 = rowok ? av1b[r] : 0.f;
        #pragma unroll
        for (int j = 0; j < 8; ++j) {
          float v = acc[q][j];
          v += __shfl_xor(v, 1); v += __shfl_xor(v, 2); v += __shfl_xor(v, 4);
          if (l8 == 0 && rowok)
            stgf(wsf + OFF_TBUF + ((size_t)b * 16 + jbase + j) * 1024 + r, fmaxf(v + b1, 0.f));
        }
      }
    }
  }
  __syncthreads();
  if (tid == 0)
    __hip_atomic_store(F1F + b * 16 + rs, 1u, __ATOMIC_RELAXED, __HIP_MEMORY_SCOPE_AGENT);

  // ---- F2: all 120 edges per batch ----
  const float* ae1b = a.in[10]; const float* ae2w = a.in[11]; const float* ae2b = a.in[12];
  const int rbase = rs * 126 + il * 4;
  for (int chunk = 0; chunk < 15; ++chunk) {
    int idxs[8], vjs[8]; bool tval[8];
    #pragma unroll
    for (int j = 0; j < 8; ++j) {
      int e = chunk * 8 + j;
      if (e < 120) {
        int ix = 1, rem = e;
        while (rem >= ix) { rem -= ix; ++ix; }
        idxs[j] = ix; vjs[j] = rem; tval[j] = true;
      } else { idxs[j] = 1; vjs[j] = 0; tval[j] = false; }
    }
    __syncthreads();
    for (int t = tid; t < 1024; t += 256) {
      int sl = t >> 7, k4 = t & 127;
      int sE = idxs[sl] - 1 - vjs[sl];
      lds4[t] = maskpad(((const float4*)(wsf + hslotf(b, trif(idxs[sl]) + sE)))[k4], k4);
    }
    __syncthreads();
    float part[8];
    #pragma unroll
    for (int j = 0; j < 8; ++j) part[j] = 0.f;
    float acc[4][8];
    #pragma unroll
    for (int q = 0; q < 4; ++q)
      #pragma unroll
      for (int j = 0; j < 8; ++j) acc[q][j] = 0.f;
    for (int s = 0; s < 63; ++s) {
      int k = s * 8 + l8;
      if (k < 501) {
        float w[4];
        #pragma unroll
        for (int q = 0; q < 4; ++q)
          w[q] = (rbase + q < 2004) ? ae1w[(size_t)(rbase + q) * 1002 + k] : 0.f;
        float hv[8];
        #pragma unroll
        for (int j = 0; j < 8; ++j) hv[j] = smem[j * 512 + k];
        #pragma unroll
        for (int q = 0; q < 4; ++q)
          #pragma unroll
          for (int j = 0; j < 8; ++j) acc[q][j] = fmaf(w[q], hv[j], acc[q][j]);
      }
    }
    #pragma unroll
    for (int q = 0; q < 4; ++q) {
      int r = rbase + q;
      bool rowok = (il * 4 + q < 126) && (r < 2004);
      float aer = rowok ? ae2w[r] : 0.f;
      float b1r = rowok ? ae1b[r] : 0.f;
      #pragma unroll
      for (int j = 0; j < 8; ++j) {
        float v = acc[q][j];
        v += __shfl_xor(v, 1); v += __shfl_xor(v, 2); v += __shfl_xor(v, 4);
        if (l8 == 0 && rowok && tval[j]) {
          float bh = smem[F_BHJ + vjs[j] * 128 + il * 4 + q];
          part[j] = fmaf(aer, fmaxf(v + bh + b1r, 0.f), part[j]);
        }
      }
    }
    if (l8 == 0) {
      #pragma unroll
      for (int j = 0; j < 8; ++j) smem[F_RED + il * 8 + j] = part[j];
    }
    __syncthreads();
    if (tid < 8) {
      float v = 0.f;
      for (int q = 0; q < 32; ++q) v += smem[F_RED + q * 8 + tid];
      if (rs == 0) v += ae2b[0];
      if (tval[tid])
        atomicAdd(a.out + ((size_t)b * 16 + idxs[tid]) * 16 + vjs[tid], v);
    }
    __syncthreads();
  }
  // ---- F3: gen_node_encoding[(b, rs)] ----
  if (tid < 16) {
    unsigned* p = F1F + b * 16 + tid;
    while (__hip_atomic_load(p, __ATOMIC_RELAXED, __HIP_MEMORY_SCOPE_AGENT) != 1u)
      __builtin_amdgcn_s_sleep(2);
  }
  __syncthreads();
  {
    const float* av2w = a.in[7]; const float* av2b = a.in[8];
    const float* tb = wsf + OFF_TBUF + ((size_t)b * 16 + rs) * 1024;
    float accn[10];
    #pragma unroll
    for (int c = 0; c < 10; ++c) accn[c] = 0.f;
    for (int r = tid; r < 1002; r += 256) {
      float tv = tb[r];
      #pragma unroll
      for (int c = 0; c < 10; ++c) accn[c] = fmaf(av2w[(size_t)c * 1002 + r], tv, accn[c]);
    }
    #pragma unroll
    for (int c = 0; c < 10; ++c) {
      float v = accn[c];
      for (int m2 = 1; m2 < 64; m2 <<= 1) v += __shfl_xor(v, m2);
      if ((tid & 63) == 0) smem[F_RED + (tid >> 6) * 10 + c] = v;
    }
    __syncthreads();
    if (tid == 0) {
      for (int c = 0; c < 10; ++c) {
        float v = av2b[c] + smem[F_RED + c] + smem[F_RED + 10 + c] + smem[F_RED + 20 + c] + smem[F_RED + 30 + c];
        stgf(a.out + 4096 + ((size_t)b * 16 + rs) * 10 + c, v);
      }
    }
  }
}

extern "C" void kernel_launch(void* const* d_in, const int* in_sizes, int n_in,
                              void* d_out, int out_size, void* d_ws, size_t ws_size,
                              hipStream_t stream) {
  (void)in_sizes; (void)n_in; (void)out_size;
  if (ws_size < WS_NEED) return;   // fail loudly via validation
  KArgs a;
  for (int k = 0; k < 21; ++k) a.in[k] = (const float*)d_in[k];
  a.out = (float*)d_out;
  a.wsf = (float*)d_ws;
  k0_init<<<256, 256, 0, stream>>>(a);
  k1_scan<<<256, 256, 0, stream>>>(a);
  k2_fin <<<256, 256, 0, stream>>>(a);
}